// Round 1
// baseline (1267.648 us; speedup 1.0000x reference)
//
#include <hip/hip_runtime.h>
#include <cstdint>
#include <cstddef>

// CrossAttention baseline (fp32, correctness anchor).
// Pipeline: qg = x@Wq.T ; kv = ctx@Wkv.T ; in-place zmRMSNorm+RoPE on q,k parts;
// flash attention (fused sigmoid-gate epilogue) ; out = g@Wo.T + bo.
// ws layout: qg 32MB @0 | kv 32MB @32MB | g 16MB @64MB  (total 80MB)

#define B_ 2
#define N_ 2048
#define C_ 1024
#define H_ 16
#define D_ 64
#define EPS_ 1e-6f

// ---------- GEMM NT fp32: C[m,n] = sum_k A[m,k]*B[n,k] (+bias[n]) ----------
// A: (M,K) row-major, Bm: (N,K) row-major. 64x64 tile, BK=16, 256 thr, 4x4 micro.
__global__ __launch_bounds__(256) void gemm_nt_f32(
    const float* __restrict__ A, const float* __restrict__ Bm,
    float* __restrict__ Cm, int M, int N, int K,
    const float* __restrict__ bias)
{
  __shared__ float As[16][64];   // [k][m]
  __shared__ float Bs[16][64];   // [k][n]
  const int tid = threadIdx.x;
  const int tx = tid & 15, ty = tid >> 4;
  const int bm = blockIdx.y * 64, bn = blockIdx.x * 64;
  const int lr = tid >> 2, lk = (tid & 3) << 2;   // 64 rows x 4-float chunk
  const float* Ap = A + (size_t)(bm + lr) * K + lk;
  const float* Bp = Bm + (size_t)(bn + lr) * K + lk;
  float acc[4][4] = {};
  for (int k0 = 0; k0 < K; k0 += 16) {
    float4 a4 = *(const float4*)(Ap + k0);
    float4 b4 = *(const float4*)(Bp + k0);
    As[lk+0][lr] = a4.x; As[lk+1][lr] = a4.y; As[lk+2][lr] = a4.z; As[lk+3][lr] = a4.w;
    Bs[lk+0][lr] = b4.x; Bs[lk+1][lr] = b4.y; Bs[lk+2][lr] = b4.z; Bs[lk+3][lr] = b4.w;
    __syncthreads();
    #pragma unroll
    for (int k = 0; k < 16; ++k) {
      float4 av = *(const float4*)&As[k][ty*4];
      float4 bv = *(const float4*)&Bs[k][tx*4];
      float a[4] = {av.x, av.y, av.z, av.w};
      float b[4] = {bv.x, bv.y, bv.z, bv.w};
      #pragma unroll
      for (int i = 0; i < 4; ++i)
        #pragma unroll
        for (int j = 0; j < 4; ++j)
          acc[i][j] = fmaf(a[i], b[j], acc[i][j]);
    }
    __syncthreads();
  }
  #pragma unroll
  for (int i = 0; i < 4; ++i) {
    const int m = bm + ty*4 + i;
    #pragma unroll
    for (int j = 0; j < 4; ++j) {
      const int n = bn + tx*4 + j;
      float v = acc[i][j];
      if (bias) v += bias[n];
      Cm[(size_t)m * N + n] = v;
    }
  }
}

// ---------- fused zero-mean RMSNorm + RoPE, in place on q/k part ----------
// src: (B,N,2C) = (B,N,H,128); lanes 0..63 = the D values of one (b,n,h) row.
__device__ __forceinline__ float wave_sum64(float v) {
  #pragma unroll
  for (int off = 1; off < 64; off <<= 1) v += __shfl_xor(v, off);
  return v;
}

__global__ __launch_bounds__(256) void norm_rope_inplace(
    float* __restrict__ src, const float* __restrict__ cosb,
    const float* __restrict__ sinb, const float* __restrict__ nw)
{
  const int wid  = blockIdx.x * 4 + (threadIdx.x >> 6);
  const int lane = threadIdx.x & 63;
  const int h = wid % H_;
  const int n = (wid / H_) % N_;
  const int b = wid / (H_ * N_);
  const size_t base = (size_t)(b * N_ + n) * (2 * C_) + h * 128;
  float v = src[base + lane];
  const float mean = wave_sum64(v) * (1.f / 64.f);
  const float c = v - mean;
  const float var = wave_sum64(c * c) * (1.f / 64.f);
  const float x = c * rsqrtf(var + EPS_) * nw[lane];
  const float part = __shfl_xor(x, 32);               // element d^32
  const float rot = (lane < 32) ? -part : part;       // rotate_half
  const size_t ci = (size_t)(b * N_ + n) * D_ + lane;
  src[base + lane] = x * cosb[ci] + rot * sinb[ci];
}

// ---------- flash attention fp32 + fused sigmoid gate ----------
// Q,K read (normed+roped) from qg/kv in (B,N,H,128) layout; V from kv (+64 offset).
// Block: (qtile=64, h, b), 256 thr (16x16), 4x4 register micro-tiles.
__global__ __launch_bounds__(256) void flash_attn_f32(
    const float* __restrict__ qg, const float* __restrict__ kv,
    float* __restrict__ gout)
{
  const int b = blockIdx.z, h = blockIdx.y, q0 = blockIdx.x * 64;
  __shared__ float Qt[64][64];    // [d][qi]
  __shared__ float KVt[64][64];   // K phase: [d][j]; V phase: [j][d]
  __shared__ float Ps[64][68];
  const int tid = threadIdx.x;
  const int tx = tid & 15, ty = tid >> 4;

  const float* Qsrc = qg + (size_t)(b * N_ + q0) * (2 * C_) + h * 128;
  #pragma unroll
  for (int it = 0; it < 4; ++it) {
    const int i = tid + it * 256;          // 1024 float4 = 64 rows x 16 chunks
    const int r = i >> 4, d4 = (i & 15) << 2;
    float4 v = *(const float4*)(Qsrc + (size_t)r * (2 * C_) + d4);
    Qt[d4+0][r] = v.x; Qt[d4+1][r] = v.y; Qt[d4+2][r] = v.z; Qt[d4+3][r] = v.w;
  }

  float m[4], l[4], acc[4][4];
  #pragma unroll
  for (int i = 0; i < 4; ++i) {
    m[i] = -1e30f; l[i] = 0.f;
    #pragma unroll
    for (int j = 0; j < 4; ++j) acc[i][j] = 0.f;
  }

  const float* Ksrc = kv + (size_t)b * N_ * (2 * C_) + h * 128;
  const float* Vsrc = Ksrc + 64;
  __syncthreads();

  for (int j0 = 0; j0 < N_; j0 += 64) {
    // stage K transposed: KVt[d][j]
    #pragma unroll
    for (int it = 0; it < 4; ++it) {
      const int i = tid + it * 256;
      const int r = i >> 4, d4 = (i & 15) << 2;
      float4 v = *(const float4*)(Ksrc + (size_t)(j0 + r) * (2 * C_) + d4);
      KVt[d4+0][r] = v.x; KVt[d4+1][r] = v.y; KVt[d4+2][r] = v.z; KVt[d4+3][r] = v.w;
    }
    __syncthreads();

    float S[4][4] = {};
    #pragma unroll
    for (int d = 0; d < 64; ++d) {
      float4 qv = *(const float4*)&Qt[d][ty*4];
      float4 kq = *(const float4*)&KVt[d][tx*4];
      float qa[4] = {qv.x, qv.y, qv.z, qv.w};
      float ka[4] = {kq.x, kq.y, kq.z, kq.w};
      #pragma unroll
      for (int i = 0; i < 4; ++i)
        #pragma unroll
        for (int j = 0; j < 4; ++j)
          S[i][j] = fmaf(qa[i], ka[j], S[i][j]);
    }
    __syncthreads();   // done reading K; KVt free for V

    // stage V row-major: KVt[j][d]
    #pragma unroll
    for (int it = 0; it < 4; ++it) {
      const int i = tid + it * 256;
      const int r = i >> 4, d4 = (i & 15) << 2;
      float4 v = *(const float4*)(Vsrc + (size_t)(j0 + r) * (2 * C_) + d4);
      *(float4*)&KVt[r][d4] = v;
    }

    // online softmax in registers (row reduce across tx lanes: xor 1,2,4,8)
    #pragma unroll
    for (int i = 0; i < 4; ++i) {
      float mt = -1e30f;
      #pragma unroll
      for (int j = 0; j < 4; ++j) { S[i][j] *= 0.125f; mt = fmaxf(mt, S[i][j]); }
      #pragma unroll
      for (int off = 1; off < 16; off <<= 1) mt = fmaxf(mt, __shfl_xor(mt, off));
      const float mn = fmaxf(m[i], mt);
      const float al = __expf(m[i] - mn);
      float P[4], rs = 0.f;
      #pragma unroll
      for (int j = 0; j < 4; ++j) { P[j] = __expf(S[i][j] - mn); rs += P[j]; }
      #pragma unroll
      for (int off = 1; off < 16; off <<= 1) rs += __shfl_xor(rs, off);
      l[i] = l[i] * al + rs;
      m[i] = mn;
      #pragma unroll
      for (int j = 0; j < 4; ++j) acc[i][j] *= al;
      *(float4*)&Ps[ty*4+i][tx*4] = make_float4(P[0], P[1], P[2], P[3]);
    }
    __syncthreads();   // V staged + Ps visible

    // PV: acc[i][dd] += sum_j Ps[row][j] * V[j][tx*4+dd]
    #pragma unroll 8
    for (int j = 0; j < 64; ++j) {
      float4 vv = *(const float4*)&KVt[j][tx*4];
      #pragma unroll
      for (int i = 0; i < 4; ++i) {
        const float p = Ps[ty*4+i][j];
        acc[i][0] = fmaf(p, vv.x, acc[i][0]);
        acc[i][1] = fmaf(p, vv.y, acc[i][1]);
        acc[i][2] = fmaf(p, vv.z, acc[i][2]);
        acc[i][3] = fmaf(p, vv.w, acc[i][3]);
      }
    }
    __syncthreads();   // protect KVt/Ps for next iteration
  }

  // epilogue: normalize, apply sigmoid(gate), write g (B,N,H*D)
  #pragma unroll
  for (int i = 0; i < 4; ++i) {
    const int qrow = q0 + ty*4 + i;
    const float inv = 1.f / l[i];
    #pragma unroll
    for (int j = 0; j < 4; ++j) {
      const int d = tx*4 + j;
      const float o = acc[i][j] * inv;
      const float gate = qg[(size_t)(b * N_ + qrow) * (2 * C_) + h * 128 + 64 + d];
      const float sg = 1.f / (1.f + __expf(-gate));
      gout[(size_t)(b * N_ + qrow) * C_ + h * 64 + d] = o * sg;
    }
  }
}

extern "C" void kernel_launch(void* const* d_in, const int* in_sizes, int n_in,
                              void* d_out, int out_size, void* d_ws, size_t ws_size,
                              hipStream_t stream) {
  const float* x    = (const float*)d_in[0];
  const float* ctx  = (const float*)d_in[1];
  const float* cosb = (const float*)d_in[2];
  const float* sinb = (const float*)d_in[3];
  const float* Wq   = (const float*)d_in[4];
  const float* Wkv  = (const float*)d_in[5];
  const float* Wo   = (const float*)d_in[6];
  const float* bo   = (const float*)d_in[7];
  const float* qnw  = (const float*)d_in[8];
  const float* knw  = (const float*)d_in[9];
  float* out = (float*)d_out;

  char* ws = (char*)d_ws;
  float* qg = (float*)(ws);                      // (B,N,2C) 32MB
  float* kv = (float*)(ws + (size_t)33554432);   // (B,N,2C) 32MB
  float* gb = (float*)(ws + (size_t)67108864);   // (B,N,C)  16MB

  const dim3 blk(256);
  // qg = x @ Wq.T   (M=4096, N=2048, K=1024)
  gemm_nt_f32<<<dim3(2048/64, 4096/64), blk, 0, stream>>>(x,   Wq,  qg, 4096, 2048, 1024, nullptr);
  // kv = ctx @ Wkv.T
  gemm_nt_f32<<<dim3(2048/64, 4096/64), blk, 0, stream>>>(ctx, Wkv, kv, 4096, 2048, 1024, nullptr);
  // zmRMSNorm + RoPE in place on q part of qg, k part of kv
  norm_rope_inplace<<<dim3(B_*N_*H_/4), blk, 0, stream>>>(qg, cosb, sinb, qnw);
  norm_rope_inplace<<<dim3(B_*N_*H_/4), blk, 0, stream>>>(kv, cosb, sinb, knw);
  // flash attention + gate
  flash_attn_f32<<<dim3(N_/64, H_, B_), blk, 0, stream>>>(qg, kv, gb);
  // out = g @ Wo.T + bo  (M=4096, N=1024, K=1024)
  gemm_nt_f32<<<dim3(1024/64, 4096/64), blk, 0, stream>>>(gb, Wo, out, 4096, 1024, 1024, bo);
}

// Round 2
// 789.065 us; speedup vs baseline: 1.6065x; 1.6065x over previous
//
#include <hip/hip_runtime.h>
#include <cstdint>
#include <cstddef>

// CrossAttention: fp32 GEMMs (unchanged anchor) + bf16 MFMA flash attention.
// Pipeline: qg=x@Wq.T ; kv=ctx@Wkv.T ; prep: zmRMSNorm+RoPE -> Qb,Kb (bf16,
// (B,H,N,D)), V -> Vt (bf16, (B,H,D,N)) ; flash_bf16 (MFMA, fused gate) ;
// out = g@Wo.T + bo.
// ws: qg 32MB@0 | kv 32MB@32M | gb 16MB@64M | Qb 8MB@80M | Kb 8MB@88M | Vt 8MB@96M

#define B_ 2
#define N_ 2048
#define C_ 1024
#define H_ 16
#define D_ 64
#define EPS_ 1e-6f

typedef __bf16 b16x8 __attribute__((ext_vector_type(8)));
typedef float f32x4 __attribute__((ext_vector_type(4)));

__device__ __forceinline__ unsigned short f2bf(float f) {
  union { float f; unsigned u; } a; a.f = f;
  unsigned r = a.u + 0x7FFFu + ((a.u >> 16) & 1u);
  return (unsigned short)(r >> 16);
}

// ---------- GEMM NT fp32 (unchanged) ----------
__global__ __launch_bounds__(256) void gemm_nt_f32(
    const float* __restrict__ A, const float* __restrict__ Bm,
    float* __restrict__ Cm, int M, int N, int K,
    const float* __restrict__ bias)
{
  __shared__ float As[16][64];
  __shared__ float Bs[16][64];
  const int tid = threadIdx.x;
  const int tx = tid & 15, ty = tid >> 4;
  const int bm = blockIdx.y * 64, bn = blockIdx.x * 64;
  const int lr = tid >> 2, lk = (tid & 3) << 2;
  const float* Ap = A + (size_t)(bm + lr) * K + lk;
  const float* Bp = Bm + (size_t)(bn + lr) * K + lk;
  float acc[4][4] = {};
  for (int k0 = 0; k0 < K; k0 += 16) {
    float4 a4 = *(const float4*)(Ap + k0);
    float4 b4 = *(const float4*)(Bp + k0);
    As[lk+0][lr] = a4.x; As[lk+1][lr] = a4.y; As[lk+2][lr] = a4.z; As[lk+3][lr] = a4.w;
    Bs[lk+0][lr] = b4.x; Bs[lk+1][lr] = b4.y; Bs[lk+2][lr] = b4.z; Bs[lk+3][lr] = b4.w;
    __syncthreads();
    #pragma unroll
    for (int k = 0; k < 16; ++k) {
      float4 av = *(const float4*)&As[k][ty*4];
      float4 bv = *(const float4*)&Bs[k][tx*4];
      float a[4] = {av.x, av.y, av.z, av.w};
      float b[4] = {bv.x, bv.y, bv.z, bv.w};
      #pragma unroll
      for (int i = 0; i < 4; ++i)
        #pragma unroll
        for (int j = 0; j < 4; ++j)
          acc[i][j] = fmaf(a[i], b[j], acc[i][j]);
    }
    __syncthreads();
  }
  #pragma unroll
  for (int i = 0; i < 4; ++i) {
    const int m = bm + ty*4 + i;
    #pragma unroll
    for (int j = 0; j < 4; ++j) {
      const int n = bn + tx*4 + j;
      float v = acc[i][j];
      if (bias) v += bias[n];
      Cm[(size_t)m * N + n] = v;
    }
  }
}

// ---------- zmRMSNorm + RoPE -> bf16 (B,H,N,D) ----------
__device__ __forceinline__ float wave_sum64(float v) {
  #pragma unroll
  for (int off = 1; off < 64; off <<= 1) v += __shfl_xor(v, off);
  return v;
}

__global__ __launch_bounds__(256) void nr2bf(
    const float* __restrict__ src, unsigned short* __restrict__ dst,
    const float* __restrict__ cosb, const float* __restrict__ sinb,
    const float* __restrict__ nw, float oscale)
{
  const int wid  = blockIdx.x * 4 + (threadIdx.x >> 6);
  const int lane = threadIdx.x & 63;
  const int h = wid % H_;
  const int n = (wid / H_) % N_;
  const int b = wid / (H_ * N_);
  const size_t base = (size_t)(b * N_ + n) * (2 * C_) + h * 128;
  float v = src[base + lane];
  const float mean = wave_sum64(v) * (1.f / 64.f);
  const float c = v - mean;
  const float var = wave_sum64(c * c) * (1.f / 64.f);
  const float x = c * rsqrtf(var + EPS_) * nw[lane];
  const float part = __shfl_xor(x, 32);
  const float rot = (lane < 32) ? -part : part;
  const size_t ci = (size_t)(b * N_ + n) * D_ + lane;
  const float res = (x * cosb[ci] + rot * sinb[ci]) * oscale;
  dst[((size_t)(b * H_ + h) * N_ + n) * D_ + lane] = f2bf(res);
}

// ---------- V -> bf16 transposed (B,H,D,N) ----------
__global__ __launch_bounds__(256) void vtprep(
    const float* __restrict__ kv, unsigned short* __restrict__ vt)
{
  const int b = blockIdx.z, h = blockIdx.y, n0 = blockIdx.x * 64;
  __shared__ __align__(16) unsigned short Vs[64][72];
  const int tid = threadIdx.x;
  #pragma unroll
  for (int it = 0; it < 4; ++it) {
    int idx = tid + it * 256;
    int r = idx >> 4, d4 = (idx & 15) << 2;
    float4 v = *(const float4*)(kv + (size_t)(b * N_ + n0 + r) * (2*C_) + h*128 + 64 + d4);
    Vs[d4+0][r] = f2bf(v.x); Vs[d4+1][r] = f2bf(v.y);
    Vs[d4+2][r] = f2bf(v.z); Vs[d4+3][r] = f2bf(v.w);
  }
  __syncthreads();
  typedef unsigned short u16x8 __attribute__((ext_vector_type(8)));
  #pragma unroll
  for (int it = 0; it < 2; ++it) {
    int c = tid + it * 256;
    int d = c >> 3, cb = (c & 7) << 3;
    u16x8 v = *(const u16x8*)&Vs[d][cb];
    *(u16x8*)(vt + ((size_t)(b*H_+h)*D_ + d) * N_ + n0 + cb) = v;
  }
}

// ---------- bf16 MFMA flash attention + fused sigmoid gate ----------
// 256 thr = 4 waves; wave w owns q rows q0+16w..+15. KV tiles of 64.
// K,Vt staged via global_load_lds with pre-swizzled source (byte ^= (row&7)<<4).
__global__ __launch_bounds__(256) void flash_bf16(
    const unsigned short* __restrict__ Qb, const unsigned short* __restrict__ Kb,
    const unsigned short* __restrict__ Vt, const float* __restrict__ qg,
    float* __restrict__ gout)
{
  const int b = blockIdx.z, h = blockIdx.y, q0 = blockIdx.x * 64;
  const int tid = threadIdx.x, lane = tid & 63, wave = tid >> 6;
  __shared__ __align__(16) unsigned short Ks[64*64];
  __shared__ __align__(16) unsigned short Vss[64*64];
  __shared__ __align__(16) unsigned short Ps[4][16][72];
  const int bh = b * H_ + h;

  // Q fragments (A-operand: row=lane&15, 8 contiguous k per lane-group)
  b16x8 qf0, qf1;
  {
    const unsigned short* Qrow = Qb + ((size_t)bh * N_ + q0 + wave*16 + (lane & 15)) * D_;
    qf0 = *(const b16x8*)(Qrow + ((lane >> 4) << 3));
    qf1 = *(const b16x8*)(Qrow + 32 + ((lane >> 4) << 3));
  }

  f32x4 acc[4];
  float mreg[4], lreg[4];
  #pragma unroll
  for (int r = 0; r < 4; ++r) {
    mreg[r] = -1e30f; lreg[r] = 0.f;
    acc[r] = (f32x4){0.f, 0.f, 0.f, 0.f};
  }

  const unsigned short* Kbh  = Kb + (size_t)bh * N_ * D_;
  const unsigned short* Vtbh = Vt + (size_t)bh * D_ * N_;
  const int swz16 = (((lane & 7) ^ (lane >> 3)) << 4);
  const int rsub = lane >> 3;

  for (int j0 = 0; j0 < N_; j0 += 64) {
    // ---- stage K tile [64 kv][64 d] and Vt tile [64 d][64 kv] (swizzled) ----
    #pragma unroll
    for (int it = 0; it < 2; ++it) {
      const int rowi = (it*4 + wave)*8 + rsub;
      const char* ksrc = (const char*)(Kbh + (size_t)(j0 + rowi) * D_) + swz16;
      const char* vsrc = (const char*)(Vtbh + (size_t)rowi * N_ + j0) + swz16;
      __builtin_amdgcn_global_load_lds(
          (const __attribute__((address_space(1))) void*)ksrc,
          (__attribute__((address_space(3))) void*)((char*)Ks + (it*4+wave)*1024),
          16, 0, 0);
      __builtin_amdgcn_global_load_lds(
          (const __attribute__((address_space(1))) void*)vsrc,
          (__attribute__((address_space(3))) void*)((char*)Vss + (it*4+wave)*1024),
          16, 0, 0);
    }
    __syncthreads();

    // ---- QK^T: S[16q x 64kv] per wave ----
    f32x4 sacc[4];
    const int cb0 = ((lane >> 4) << 4);
    #pragma unroll
    for (int t = 0; t < 4; ++t) {
      sacc[t] = (f32x4){0.f, 0.f, 0.f, 0.f};
      const int krow = t*16 + (lane & 15);
      const int kb = krow * 128;
      const int f = (krow & 7) << 4;
      b16x8 kf0 = *(const b16x8*)((const char*)Ks + kb + (cb0 ^ f));
      b16x8 kf1 = *(const b16x8*)((const char*)Ks + kb + ((64 + cb0) ^ f));
      sacc[t] = __builtin_amdgcn_mfma_f32_16x16x32_bf16(qf0, kf0, sacc[t], 0, 0, 0);
      sacc[t] = __builtin_amdgcn_mfma_f32_16x16x32_bf16(qf1, kf1, sacc[t], 0, 0, 0);
    }

    // ---- online softmax (wave-parallel, 16-lane row groups) ----
    #pragma unroll
    for (int r = 0; r < 4; ++r) {
      const float s0 = sacc[0][r], s1 = sacc[1][r], s2 = sacc[2][r], s3 = sacc[3][r];
      float mt = fmaxf(fmaxf(s0, s1), fmaxf(s2, s3));
      #pragma unroll
      for (int off = 1; off < 16; off <<= 1) mt = fmaxf(mt, __shfl_xor(mt, off));
      const float mn = fmaxf(mreg[r], mt);
      const float al = __expf(mreg[r] - mn);
      const float p0 = __expf(s0 - mn), p1 = __expf(s1 - mn);
      const float p2 = __expf(s2 - mn), p3 = __expf(s3 - mn);
      float rs = (p0 + p1) + (p2 + p3);
      #pragma unroll
      for (int off = 1; off < 16; off <<= 1) rs += __shfl_xor(rs, off);
      lreg[r] = lreg[r] * al + rs;
      mreg[r] = mn;
      acc[0][r] *= al; acc[1][r] *= al; acc[2][r] *= al; acc[3][r] *= al;
      unsigned short* pw = &Ps[wave][((lane >> 4) << 2) + r][lane & 15];
      pw[0]  = f2bf(p0); pw[16] = f2bf(p1); pw[32] = f2bf(p2); pw[48] = f2bf(p3);
    }

    // ---- PV: O[16q x 64d] += P @ V ----
    b16x8 pf0 = *(const b16x8*)(&Ps[wave][lane & 15][(lane >> 4) << 3]);
    b16x8 pf1 = *(const b16x8*)(&Ps[wave][lane & 15][32 + ((lane >> 4) << 3)]);
    #pragma unroll
    for (int dt = 0; dt < 4; ++dt) {
      const int vrow = dt*16 + (lane & 15);
      const int vb = vrow * 128;
      const int f = (vrow & 7) << 4;
      b16x8 vf0 = *(const b16x8*)((const char*)Vss + vb + (cb0 ^ f));
      b16x8 vf1 = *(const b16x8*)((const char*)Vss + vb + ((64 + cb0) ^ f));
      acc[dt] = __builtin_amdgcn_mfma_f32_16x16x32_bf16(pf0, vf0, acc[dt], 0, 0, 0);
      acc[dt] = __builtin_amdgcn_mfma_f32_16x16x32_bf16(pf1, vf1, acc[dt], 0, 0, 0);
    }
    __syncthreads();
  }

  // ---- epilogue: normalize, sigmoid gate, write g (B,N,H*D) fp32 ----
  #pragma unroll
  for (int r = 0; r < 4; ++r) {
    const int row = ((lane >> 4) << 2) + r;
    const int q = q0 + wave*16 + row;
    const float inv = 1.f / lreg[r];
    #pragma unroll
    for (int dt = 0; dt < 4; ++dt) {
      const int d = dt*16 + (lane & 15);
      const float o = acc[dt][r] * inv;
      const float gate = qg[(size_t)(b*N_ + q) * (2*C_) + h*128 + 64 + d];
      const float sg = 1.f / (1.f + __expf(-gate));
      gout[(size_t)(b*N_ + q) * C_ + h*64 + d] = o * sg;
    }
  }
}

extern "C" void kernel_launch(void* const* d_in, const int* in_sizes, int n_in,
                              void* d_out, int out_size, void* d_ws, size_t ws_size,
                              hipStream_t stream) {
  const float* x    = (const float*)d_in[0];
  const float* ctx  = (const float*)d_in[1];
  const float* cosb = (const float*)d_in[2];
  const float* sinb = (const float*)d_in[3];
  const float* Wq   = (const float*)d_in[4];
  const float* Wkv  = (const float*)d_in[5];
  const float* Wo   = (const float*)d_in[6];
  const float* bo   = (const float*)d_in[7];
  const float* qnw  = (const float*)d_in[8];
  const float* knw  = (const float*)d_in[9];
  float* out = (float*)d_out;

  char* ws = (char*)d_ws;
  float* qg = (float*)(ws);
  float* kv = (float*)(ws + (size_t)33554432);
  float* gb = (float*)(ws + (size_t)67108864);
  unsigned short* Qb = (unsigned short*)(ws + (size_t)83886080);
  unsigned short* Kb = (unsigned short*)(ws + (size_t)92274688);
  unsigned short* Vt = (unsigned short*)(ws + (size_t)100663296);

  const dim3 blk(256);
  gemm_nt_f32<<<dim3(32, 64), blk, 0, stream>>>(x,   Wq,  qg, 4096, 2048, 1024, nullptr);
  gemm_nt_f32<<<dim3(32, 64), blk, 0, stream>>>(ctx, Wkv, kv, 4096, 2048, 1024, nullptr);
  nr2bf<<<dim3(B_*N_*H_/4), blk, 0, stream>>>(qg, Qb, cosb, sinb, qnw, 0.125f);
  nr2bf<<<dim3(B_*N_*H_/4), blk, 0, stream>>>(kv, Kb, cosb, sinb, knw, 1.0f);
  vtprep<<<dim3(N_/64, H_, B_), blk, 0, stream>>>(kv, Vt);
  flash_bf16<<<dim3(N_/64, H_, B_), blk, 0, stream>>>(Qb, Kb, Vt, qg, gb);
  gemm_nt_f32<<<dim3(16, 64), blk, 0, stream>>>(gb, Wo, out, 4096, 1024, 1024, bo);
}

// Round 3
// 314.859 us; speedup vs baseline: 4.0261x; 2.5061x over previous
//
#include <hip/hip_runtime.h>
#include <cstdint>
#include <cstddef>

// CrossAttention: split-bf16 (hi/lo, 3-MFMA) projections + bf16 MFMA flash attn.
// Pipeline: pack x,Wq -> gemm1 (qg fp32) ; pack ctx,Wkv -> gemm2 (kv fp32) ;
// nr2bf (zmRMSNorm+RoPE -> Qb,Kb bf16) ; vtprep (V -> Vt bf16 transposed) ;
// flash (MFMA, fused sigmoid gate, writes hi/lo-packed gp) ; gemm3 -> out.
//
// Packed layout P(R, 2K): row r, k-chunk c (32 k): P[r][c*64+j]=hi, P[r][c*64+32+j]=lo.
// ws (peak 100MB, lifetime-overlapped):
//  qg fp32 32MB @0          | xp 16MB @32M -> kv fp32 32MB @32M -> gp 16MB @32M
//  cp 16MB @64M -> Qb 8MB @64M, Kb 8MB @72M | Vt 8MB @80M
//  wqp 8MB @88M -> wkvp 8MB @88M | wop 4MB @96M

#define B_ 2
#define N_ 2048
#define C_ 1024
#define H_ 16
#define D_ 64
#define K_ 1024
#define PK_ 2048
#define EPS_ 1e-6f

typedef __bf16 b16x8 __attribute__((ext_vector_type(8)));
typedef float f32x4 __attribute__((ext_vector_type(4)));

__device__ __forceinline__ unsigned short f2bf(float f) {
  union { float f; unsigned u; } a; a.f = f;
  unsigned r = a.u + 0x7FFFu + ((a.u >> 16) & 1u);
  return (unsigned short)(r >> 16);
}
__device__ __forceinline__ float bf2f(unsigned short u) {
  union { unsigned u; float f; } a; a.u = ((unsigned)u) << 16; return a.f;
}

// ---------- pack fp32 (R,1024) -> hi/lo bf16 (R,2048) ----------
__global__ __launch_bounds__(256) void pack_hilo(
    const float* __restrict__ X, unsigned short* __restrict__ P, int total)
{
  const int idx = blockIdx.x * 256 + threadIdx.x;
  const int e = idx << 2;
  if (e >= total) return;
  float4 v = *(const float4*)(X + e);
  const int r = e >> 10, k = e & 1023;
  unsigned short* p = P + ((size_t)r << 11) + ((k >> 5) << 6) + (k & 31);
  const unsigned short h0 = f2bf(v.x), h1 = f2bf(v.y), h2 = f2bf(v.z), h3 = f2bf(v.w);
  *(ushort4*)p = make_ushort4(h0, h1, h2, h3);
  *(ushort4*)(p + 32) = make_ushort4(f2bf(v.x - bf2f(h0)), f2bf(v.y - bf2f(h1)),
                                     f2bf(v.z - bf2f(h2)), f2bf(v.w - bf2f(h3)));
}

// ---------- split-bf16 GEMM NT: C = A @ B.T (+bias), fp32 out ----------
// Ap (M,2K) packed, Bp (N,2K) packed. 128x128 tile, BK=32, 4 waves (2x2 of 64x64).
__global__ __launch_bounds__(256) void gemm_nt_hilo(
    const unsigned short* __restrict__ Ap, const unsigned short* __restrict__ Bp,
    float* __restrict__ Cm, int M, int N, const float* __restrict__ bias)
{
  __shared__ __align__(16) unsigned short As[128 * 64];  // 128B swizzled rows
  __shared__ __align__(16) unsigned short Bs[128 * 64];
  const int tid = threadIdx.x, lane = tid & 63, wave = tid >> 6;

  // XCD-bijective remap (gridDim.x % 8 == 0)
  const int nwg = gridDim.x, id = blockIdx.x;
  const int swz = (id & 7) * (nwg >> 3) + (id >> 3);
  const int nbn = N >> 7;
  const int bm = (swz / nbn) << 7, bn = (swz % nbn) << 7;
  const int wm = (wave >> 1) << 6, wn = (wave & 1) << 6;

  // staging: pre-swizzled global source, linear LDS dest (rule 21)
  const int srow = lane >> 3;
  const int sslot = (lane & 7) ^ srow;
  const size_t rbytes = (size_t)K_ * 4;  // 2K ushorts per packed row
  const char* aSrc = (const char*)Ap + (size_t)(bm + srow) * rbytes + (sslot << 4);
  const char* bSrc = (const char*)Bp + (size_t)(bn + srow) * rbytes + (sslot << 4);

  f32x4 acc[4][4];
  #pragma unroll
  for (int i = 0; i < 4; ++i)
    #pragma unroll
    for (int j = 0; j < 4; ++j) acc[i][j] = (f32x4){0.f, 0.f, 0.f, 0.f};

  const int fr = lane & 15, fs = lane >> 4;
  const int hoff = (fs ^ (fr & 7)) << 4;   // hi slot byte offset; lo = hoff ^ 64

  for (int ks = 0; ks < K_ / 32; ++ks) {
    const size_t ko = (size_t)ks << 7;
    #pragma unroll
    for (int i = 0; i < 4; ++i) {
      const int g = (wave << 2) + i;       // 8-row group 0..15
      __builtin_amdgcn_global_load_lds(
          (const __attribute__((address_space(1))) void*)(aSrc + (size_t)(g << 3) * rbytes + ko),
          (__attribute__((address_space(3))) void*)((char*)As + (g << 10)), 16, 0, 0);
      __builtin_amdgcn_global_load_lds(
          (const __attribute__((address_space(1))) void*)(bSrc + (size_t)(g << 3) * rbytes + ko),
          (__attribute__((address_space(3))) void*)((char*)Bs + (g << 10)), 16, 0, 0);
    }
    __syncthreads();

    b16x8 ah[4], al[4], bh[4], bl[4];
    #pragma unroll
    for (int t = 0; t < 4; ++t) {
      const char* pa = (const char*)As + ((wm + (t << 4) + fr) << 7);
      ah[t] = *(const b16x8*)(pa + hoff);
      al[t] = *(const b16x8*)(pa + (hoff ^ 64));
      const char* pb = (const char*)Bs + ((wn + (t << 4) + fr) << 7);
      bh[t] = *(const b16x8*)(pb + hoff);
      bl[t] = *(const b16x8*)(pb + (hoff ^ 64));
    }
    #pragma unroll
    for (int mi = 0; mi < 4; ++mi)
      #pragma unroll
      for (int ni = 0; ni < 4; ++ni) {
        acc[mi][ni] = __builtin_amdgcn_mfma_f32_16x16x32_bf16(ah[mi], bh[ni], acc[mi][ni], 0, 0, 0);
        acc[mi][ni] = __builtin_amdgcn_mfma_f32_16x16x32_bf16(al[mi], bh[ni], acc[mi][ni], 0, 0, 0);
        acc[mi][ni] = __builtin_amdgcn_mfma_f32_16x16x32_bf16(ah[mi], bl[ni], acc[mi][ni], 0, 0, 0);
      }
    __syncthreads();
  }

  const int rbase = (lane >> 4) << 2;
  #pragma unroll
  for (int mi = 0; mi < 4; ++mi)
    #pragma unroll
    for (int ni = 0; ni < 4; ++ni) {
      const int n = bn + wn + (ni << 4) + (lane & 15);
      const float badd = bias ? bias[n] : 0.f;
      #pragma unroll
      for (int r = 0; r < 4; ++r) {
        const int m = bm + wm + (mi << 4) + rbase + r;
        Cm[(size_t)m * N + n] = acc[mi][ni][r] + badd;
      }
    }
}

// ---------- zmRMSNorm + RoPE -> bf16 (B,H,N,D) ----------
__device__ __forceinline__ float wave_sum64(float v) {
  #pragma unroll
  for (int off = 1; off < 64; off <<= 1) v += __shfl_xor(v, off);
  return v;
}

__global__ __launch_bounds__(256) void nr2bf(
    const float* __restrict__ src, unsigned short* __restrict__ dst,
    const float* __restrict__ cosb, const float* __restrict__ sinb,
    const float* __restrict__ nw, float oscale)
{
  const int wid  = blockIdx.x * 4 + (threadIdx.x >> 6);
  const int lane = threadIdx.x & 63;
  const int h = wid % H_;
  const int n = (wid / H_) % N_;
  const int b = wid / (H_ * N_);
  const size_t base = (size_t)(b * N_ + n) * (2 * C_) + h * 128;
  float v = src[base + lane];
  const float mean = wave_sum64(v) * (1.f / 64.f);
  const float c = v - mean;
  const float var = wave_sum64(c * c) * (1.f / 64.f);
  const float x = c * rsqrtf(var + EPS_) * nw[lane];
  const float part = __shfl_xor(x, 32);
  const float rot = (lane < 32) ? -part : part;
  const size_t ci = (size_t)(b * N_ + n) * D_ + lane;
  const float res = (x * cosb[ci] + rot * sinb[ci]) * oscale;
  dst[((size_t)(b * H_ + h) * N_ + n) * D_ + lane] = f2bf(res);
}

// ---------- V -> bf16 transposed (B,H,D,N) ----------
__global__ __launch_bounds__(256) void vtprep(
    const float* __restrict__ kv, unsigned short* __restrict__ vt)
{
  const int b = blockIdx.z, h = blockIdx.y, n0 = blockIdx.x * 64;
  __shared__ __align__(16) unsigned short Vs[64][72];
  const int tid = threadIdx.x;
  #pragma unroll
  for (int it = 0; it < 4; ++it) {
    int idx = tid + it * 256;
    int r = idx >> 4, d4 = (idx & 15) << 2;
    float4 v = *(const float4*)(kv + (size_t)(b * N_ + n0 + r) * (2*C_) + h*128 + 64 + d4);
    Vs[d4+0][r] = f2bf(v.x); Vs[d4+1][r] = f2bf(v.y);
    Vs[d4+2][r] = f2bf(v.z); Vs[d4+3][r] = f2bf(v.w);
  }
  __syncthreads();
  typedef unsigned short u16x8 __attribute__((ext_vector_type(8)));
  #pragma unroll
  for (int it = 0; it < 2; ++it) {
    int c = tid + it * 256;
    int d = c >> 3, cb = (c & 7) << 3;
    u16x8 v = *(const u16x8*)&Vs[d][cb];
    *(u16x8*)(vt + ((size_t)(b*H_+h)*D_ + d) * N_ + n0 + cb) = v;
  }
}

// ---------- bf16 MFMA flash attention + gate, writes hi/lo-packed gp ----------
__global__ __launch_bounds__(256) void flash_bf16(
    const unsigned short* __restrict__ Qb, const unsigned short* __restrict__ Kb,
    const unsigned short* __restrict__ Vt, const float* __restrict__ qg,
    unsigned short* __restrict__ gp)
{
  const int b = blockIdx.z, h = blockIdx.y, q0 = blockIdx.x * 64;
  const int tid = threadIdx.x, lane = tid & 63, wave = tid >> 6;
  __shared__ __align__(16) unsigned short Ks[64*64];
  __shared__ __align__(16) unsigned short Vss[64*64];
  __shared__ __align__(16) unsigned short Ps[4][16][72];
  const int bh = b * H_ + h;

  b16x8 qf0, qf1;
  {
    const unsigned short* Qrow = Qb + ((size_t)bh * N_ + q0 + wave*16 + (lane & 15)) * D_;
    qf0 = *(const b16x8*)(Qrow + ((lane >> 4) << 3));
    qf1 = *(const b16x8*)(Qrow + 32 + ((lane >> 4) << 3));
  }

  f32x4 acc[4];
  float mreg[4], lreg[4];
  #pragma unroll
  for (int r = 0; r < 4; ++r) {
    mreg[r] = -1e30f; lreg[r] = 0.f;
    acc[r] = (f32x4){0.f, 0.f, 0.f, 0.f};
  }

  const unsigned short* Kbh  = Kb + (size_t)bh * N_ * D_;
  const unsigned short* Vtbh = Vt + (size_t)bh * D_ * N_;
  const int swz16 = (((lane & 7) ^ (lane >> 3)) << 4);
  const int rsub = lane >> 3;

  for (int j0 = 0; j0 < N_; j0 += 64) {
    #pragma unroll
    for (int it = 0; it < 2; ++it) {
      const int rowi = (it*4 + wave)*8 + rsub;
      const char* ksrc = (const char*)(Kbh + (size_t)(j0 + rowi) * D_) + swz16;
      const char* vsrc = (const char*)(Vtbh + (size_t)rowi * N_ + j0) + swz16;
      __builtin_amdgcn_global_load_lds(
          (const __attribute__((address_space(1))) void*)ksrc,
          (__attribute__((address_space(3))) void*)((char*)Ks + (it*4+wave)*1024),
          16, 0, 0);
      __builtin_amdgcn_global_load_lds(
          (const __attribute__((address_space(1))) void*)vsrc,
          (__attribute__((address_space(3))) void*)((char*)Vss + (it*4+wave)*1024),
          16, 0, 0);
    }
    __syncthreads();

    f32x4 sacc[4];
    const int cb0 = ((lane >> 4) << 4);
    #pragma unroll
    for (int t = 0; t < 4; ++t) {
      sacc[t] = (f32x4){0.f, 0.f, 0.f, 0.f};
      const int krow = t*16 + (lane & 15);
      const int kb = krow * 128;
      const int f = (krow & 7) << 4;
      b16x8 kf0 = *(const b16x8*)((const char*)Ks + kb + (cb0 ^ f));
      b16x8 kf1 = *(const b16x8*)((const char*)Ks + kb + ((64 + cb0) ^ f));
      sacc[t] = __builtin_amdgcn_mfma_f32_16x16x32_bf16(qf0, kf0, sacc[t], 0, 0, 0);
      sacc[t] = __builtin_amdgcn_mfma_f32_16x16x32_bf16(qf1, kf1, sacc[t], 0, 0, 0);
    }

    #pragma unroll
    for (int r = 0; r < 4; ++r) {
      const float s0 = sacc[0][r], s1 = sacc[1][r], s2 = sacc[2][r], s3 = sacc[3][r];
      float mt = fmaxf(fmaxf(s0, s1), fmaxf(s2, s3));
      #pragma unroll
      for (int off = 1; off < 16; off <<= 1) mt = fmaxf(mt, __shfl_xor(mt, off));
      const float mn = fmaxf(mreg[r], mt);
      const float al = __expf(mreg[r] - mn);
      const float p0 = __expf(s0 - mn), p1 = __expf(s1 - mn);
      const float p2 = __expf(s2 - mn), p3 = __expf(s3 - mn);
      float rs = (p0 + p1) + (p2 + p3);
      #pragma unroll
      for (int off = 1; off < 16; off <<= 1) rs += __shfl_xor(rs, off);
      lreg[r] = lreg[r] * al + rs;
      mreg[r] = mn;
      acc[0][r] *= al; acc[1][r] *= al; acc[2][r] *= al; acc[3][r] *= al;
      unsigned short* pw = &Ps[wave][((lane >> 4) << 2) + r][lane & 15];
      pw[0]  = f2bf(p0); pw[16] = f2bf(p1); pw[32] = f2bf(p2); pw[48] = f2bf(p3);
    }

    b16x8 pf0 = *(const b16x8*)(&Ps[wave][lane & 15][(lane >> 4) << 3]);
    b16x8 pf1 = *(const b16x8*)(&Ps[wave][lane & 15][32 + ((lane >> 4) << 3)]);
    #pragma unroll
    for (int dt = 0; dt < 4; ++dt) {
      const int vrow = dt*16 + (lane & 15);
      const int vb = vrow * 128;
      const int f = (vrow & 7) << 4;
      b16x8 vf0 = *(const b16x8*)((const char*)Vss + vb + (cb0 ^ f));
      b16x8 vf1 = *(const b16x8*)((const char*)Vss + vb + ((64 + cb0) ^ f));
      acc[dt] = __builtin_amdgcn_mfma_f32_16x16x32_bf16(pf0, vf0, acc[dt], 0, 0, 0);
      acc[dt] = __builtin_amdgcn_mfma_f32_16x16x32_bf16(pf1, vf1, acc[dt], 0, 0, 0);
    }
    __syncthreads();
  }

  // epilogue: normalize, sigmoid gate, write hi/lo-packed gp (B*N, 2048)
  #pragma unroll
  for (int r = 0; r < 4; ++r) {
    const int row = ((lane >> 4) << 2) + r;
    const int q = q0 + wave*16 + row;
    const float inv = 1.f / lreg[r];
    const size_t rowbase = (size_t)(b*N_ + q) * PK_;
    #pragma unroll
    for (int dt = 0; dt < 4; ++dt) {
      const int d = (dt << 4) + (lane & 15);
      const float o = acc[dt][r] * inv;
      const float gate = qg[(size_t)(b*N_ + q) * (2*C_) + h*128 + 64 + d];
      const float sg = 1.f / (1.f + __expf(-gate));
      const float val = o * sg;
      const int k = h*64 + d;
      unsigned short* p = gp + rowbase + ((k >> 5) << 6) + (k & 31);
      const unsigned short hi = f2bf(val);
      p[0]  = hi;
      p[32] = f2bf(val - bf2f(hi));
    }
  }
}

extern "C" void kernel_launch(void* const* d_in, const int* in_sizes, int n_in,
                              void* d_out, int out_size, void* d_ws, size_t ws_size,
                              hipStream_t stream) {
  const float* x    = (const float*)d_in[0];
  const float* ctx  = (const float*)d_in[1];
  const float* cosb = (const float*)d_in[2];
  const float* sinb = (const float*)d_in[3];
  const float* Wq   = (const float*)d_in[4];
  const float* Wkv  = (const float*)d_in[5];
  const float* Wo   = (const float*)d_in[6];
  const float* bo   = (const float*)d_in[7];
  const float* qnw  = (const float*)d_in[8];
  const float* knw  = (const float*)d_in[9];
  float* out = (float*)d_out;

  char* ws = (char*)d_ws;
  float* qg          = (float*)(ws);                              // 32MB, live all
  unsigned short* xp = (unsigned short*)(ws + (size_t)33554432);  // 16MB, dead after gemm1
  float* kv          = (float*)(ws + (size_t)33554432);           // 32MB, after xp dead
  unsigned short* gpk= (unsigned short*)(ws + (size_t)33554432);  // 16MB, after kv dead
  unsigned short* cp = (unsigned short*)(ws + (size_t)67108864);  // 16MB, dead after gemm2
  unsigned short* Qb = (unsigned short*)(ws + (size_t)67108864);  // 8MB, after cp dead
  unsigned short* Kb = (unsigned short*)(ws + (size_t)75497472);  // 8MB, after cp dead
  unsigned short* Vt = (unsigned short*)(ws + (size_t)83886080);  // 8MB
  unsigned short* wqp= (unsigned short*)(ws + (size_t)92274688);  // 8MB, dead after gemm1
  unsigned short* wkvp=(unsigned short*)(ws + (size_t)92274688);  // 8MB, after wqp dead
  unsigned short* wop= (unsigned short*)(ws + (size_t)100663296); // 4MB

  const dim3 blk(256);
  // pack + gemm1: qg = x @ Wq.T
  pack_hilo<<<dim3(4096), blk, 0, stream>>>(x,  xp,  4096*1024);
  pack_hilo<<<dim3(2048), blk, 0, stream>>>(Wq, wqp, 2048*1024);
  pack_hilo<<<dim3(4096), blk, 0, stream>>>(ctx, cp, 4096*1024);
  gemm_nt_hilo<<<dim3(512), blk, 0, stream>>>(xp, wqp, qg, 4096, 2048, nullptr);
  // pack + gemm2: kv = ctx @ Wkv.T   (wkvp reuses wqp slot -> after gemm1)
  pack_hilo<<<dim3(2048), blk, 0, stream>>>(Wkv, wkvp, 2048*1024);
  gemm_nt_hilo<<<dim3(512), blk, 0, stream>>>(cp, wkvp, kv, 4096, 2048, nullptr);
  // norm/rope/V-transpose preps (Qb/Kb reuse cp slot -> after gemm2)
  nr2bf<<<dim3(B_*N_*H_/4), blk, 0, stream>>>(qg, Qb, cosb, sinb, qnw, 0.125f);
  nr2bf<<<dim3(B_*N_*H_/4), blk, 0, stream>>>(kv, Kb, cosb, sinb, knw, 1.0f);
  vtprep<<<dim3(N_/64, H_, B_), blk, 0, stream>>>(kv, Vt);
  pack_hilo<<<dim3(1024), blk, 0, stream>>>(Wo, wop, 1024*1024);
  // flash attention (gp reuses kv slot -> after vtprep)
  flash_bf16<<<dim3(N_/64, H_, B_), blk, 0, stream>>>(Qb, Kb, Vt, qg, gpk);
  // gemm3: out = g @ Wo.T + bo
  gemm_nt_hilo<<<dim3(256), blk, 0, stream>>>(gpk, wop, out, 4096, 1024, bo);
}

// Round 4
// 286.096 us; speedup vs baseline: 4.4309x; 1.1005x over previous
//
#include <hip/hip_runtime.h>
#include <cstdint>
#include <cstddef>

// CrossAttention: split-bf16 (hi/lo, 3-MFMA) projections + bf16 MFMA flash attn
// (KVBLK=128, exp2-domain softmax, defer-max, native bf16 cvt).
// Launches: pack3 | gemm1 | packWkv | gemm2 | prep_all | flash | gemm3  (7)
// ws (peak 104MiB, lifetime-aliased):
//  qg 32M@0 | kv 32M@32M -> gpk 16M@32M | cp 16M@64M -> Qb 8M@64M, Kb 8M@72M
//  xp 16M@80M -> wkvp 8M@80M -> Vt 8M@80M | wop 4M@88M | wqp 8M@96M

#define B_ 2
#define N_ 2048
#define C_ 1024
#define H_ 16
#define D_ 64
#define K_ 1024
#define PK_ 2048
#define EPS_ 1e-6f
#define LOG2E_ 1.44269504088896f

typedef __bf16 b16x8 __attribute__((ext_vector_type(8)));
typedef float f32x4 __attribute__((ext_vector_type(4)));

__device__ __forceinline__ unsigned short f2bf(float f) {
  union { float f; unsigned u; } a; a.f = f;
  unsigned r = a.u + 0x7FFFu + ((a.u >> 16) & 1u);
  return (unsigned short)(r >> 16);
}
__device__ __forceinline__ float bf2f(unsigned short u) {
  union { unsigned u; float f; } a; a.u = ((unsigned)u) << 16; return a.f;
}

// pack 4 consecutive fp32 (row-width 1024) into hi/lo bf16 chunks (row-width 2048)
__device__ __forceinline__ void pack_one(const float* __restrict__ src,
                                         unsigned short* __restrict__ dst, int e) {
  float4 v = *(const float4*)(src + e);
  const int r = e >> 10, k = e & 1023;
  unsigned short* p = dst + ((size_t)r << 11) + ((k >> 5) << 6) + (k & 31);
  const unsigned short h0 = f2bf(v.x), h1 = f2bf(v.y), h2 = f2bf(v.z), h3 = f2bf(v.w);
  *(ushort4*)p = make_ushort4(h0, h1, h2, h3);
  *(ushort4*)(p + 32) = make_ushort4(f2bf(v.x - bf2f(h0)), f2bf(v.y - bf2f(h1)),
                                     f2bf(v.z - bf2f(h2)), f2bf(v.w - bf2f(h3)));
}

__global__ __launch_bounds__(256) void pack_hilo(
    const float* __restrict__ X, unsigned short* __restrict__ P, int total)
{
  const int e = (blockIdx.x * 256 + threadIdx.x) << 2;
  if (e < total) pack_one(X, P, e);
}

// fused pack of x (4M floats), Wq (2M), ctx (4M)
__global__ __launch_bounds__(256) void pack3(
    const float* __restrict__ x, const float* __restrict__ Wq,
    const float* __restrict__ ctx, unsigned short* __restrict__ xp,
    unsigned short* __restrict__ wqp, unsigned short* __restrict__ cp)
{
  const int e = (blockIdx.x * 256 + threadIdx.x) << 2;
  if (e < 4194304)      pack_one(x,   xp,  e);
  else if (e < 6291456) pack_one(Wq,  wqp, e - 4194304);
  else                  pack_one(ctx, cp,  e - 6291456);
}

// ---------- split-bf16 GEMM NT: C = A @ B.T (+bias), fp32 out ----------
__global__ __launch_bounds__(256) void gemm_nt_hilo(
    const unsigned short* __restrict__ Ap, const unsigned short* __restrict__ Bp,
    float* __restrict__ Cm, int M, int N, const float* __restrict__ bias)
{
  __shared__ __align__(16) unsigned short As[128 * 64];
  __shared__ __align__(16) unsigned short Bs[128 * 64];
  const int tid = threadIdx.x, lane = tid & 63, wave = tid >> 6;

  const int nwg = gridDim.x, id = blockIdx.x;
  const int swz = (id & 7) * (nwg >> 3) + (id >> 3);
  const int nbn = N >> 7;
  const int bm = (swz / nbn) << 7, bn = (swz % nbn) << 7;
  const int wm = (wave >> 1) << 6, wn = (wave & 1) << 6;

  const int srow = lane >> 3;
  const int sslot = (lane & 7) ^ srow;
  const size_t rbytes = (size_t)K_ * 4;
  const char* aSrc = (const char*)Ap + (size_t)(bm + srow) * rbytes + (sslot << 4);
  const char* bSrc = (const char*)Bp + (size_t)(bn + srow) * rbytes + (sslot << 4);

  f32x4 acc[4][4];
  #pragma unroll
  for (int i = 0; i < 4; ++i)
    #pragma unroll
    for (int j = 0; j < 4; ++j) acc[i][j] = (f32x4){0.f, 0.f, 0.f, 0.f};

  const int fr = lane & 15, fs = lane >> 4;
  const int hoff = (fs ^ (fr & 7)) << 4;

  for (int ks = 0; ks < K_ / 32; ++ks) {
    const size_t ko = (size_t)ks << 7;
    #pragma unroll
    for (int i = 0; i < 4; ++i) {
      const int g = (wave << 2) + i;
      __builtin_amdgcn_global_load_lds(
          (const __attribute__((address_space(1))) void*)(aSrc + (size_t)(g << 3) * rbytes + ko),
          (__attribute__((address_space(3))) void*)((char*)As + (g << 10)), 16, 0, 0);
      __builtin_amdgcn_global_load_lds(
          (const __attribute__((address_space(1))) void*)(bSrc + (size_t)(g << 3) * rbytes + ko),
          (__attribute__((address_space(3))) void*)((char*)Bs + (g << 10)), 16, 0, 0);
    }
    __syncthreads();

    b16x8 ah[4], al[4], bh[4], bl[4];
    #pragma unroll
    for (int t = 0; t < 4; ++t) {
      const char* pa = (const char*)As + ((wm + (t << 4) + fr) << 7);
      ah[t] = *(const b16x8*)(pa + hoff);
      al[t] = *(const b16x8*)(pa + (hoff ^ 64));
      const char* pb = (const char*)Bs + ((wn + (t << 4) + fr) << 7);
      bh[t] = *(const b16x8*)(pb + hoff);
      bl[t] = *(const b16x8*)(pb + (hoff ^ 64));
    }
    #pragma unroll
    for (int mi = 0; mi < 4; ++mi)
      #pragma unroll
      for (int ni = 0; ni < 4; ++ni) {
        acc[mi][ni] = __builtin_amdgcn_mfma_f32_16x16x32_bf16(ah[mi], bh[ni], acc[mi][ni], 0, 0, 0);
        acc[mi][ni] = __builtin_amdgcn_mfma_f32_16x16x32_bf16(al[mi], bh[ni], acc[mi][ni], 0, 0, 0);
        acc[mi][ni] = __builtin_amdgcn_mfma_f32_16x16x32_bf16(ah[mi], bl[ni], acc[mi][ni], 0, 0, 0);
      }
    __syncthreads();
  }

  const int rbase = (lane >> 4) << 2;
  #pragma unroll
  for (int mi = 0; mi < 4; ++mi)
    #pragma unroll
    for (int ni = 0; ni < 4; ++ni) {
      const int n = bn + wn + (ni << 4) + (lane & 15);
      const float badd = bias ? bias[n] : 0.f;
      #pragma unroll
      for (int r = 0; r < 4; ++r) {
        const int m = bm + wm + (mi << 4) + rbase + r;
        Cm[(size_t)m * N + n] = acc[mi][ni][r] + badd;
      }
    }
}

// ---------- fused prep: q-norm->Qb | k-norm->Kb | V->Vt | pack Wo ----------
__device__ __forceinline__ float wave_sum64(float v) {
  #pragma unroll
  for (int off = 1; off < 64; off <<= 1) v += __shfl_xor(v, off);
  return v;
}

__global__ __launch_bounds__(256) void prep_all(
    const float* __restrict__ qg, const float* __restrict__ kv,
    const float* __restrict__ cosb, const float* __restrict__ sinb,
    const float* __restrict__ qnw, const float* __restrict__ knw,
    const float* __restrict__ Wo,
    unsigned short* __restrict__ Qb, unsigned short* __restrict__ Kb,
    unsigned short* __restrict__ Vtp, unsigned short* __restrict__ wop)
{
  __shared__ __align__(16) unsigned short Vs[64][72];
  const int blk = blockIdx.x, tid = threadIdx.x;
  if (blk < 32768) {
    const bool isq = blk < 16384;
    const int wid = (isq ? blk : blk - 16384) * 4 + (tid >> 6);
    const int lane = tid & 63;
    const int h = wid % H_;
    const int n = (wid / H_) % N_;
    const int b = wid / (H_ * N_);
    const float* src = isq ? qg : kv;
    const float oscale = isq ? 0.125f * LOG2E_ : 1.0f;  // fold scale+log2e into Q
    const size_t base = (size_t)(b * N_ + n) * (2 * C_) + h * 128;
    float v = src[base + lane];
    const float mean = wave_sum64(v) * (1.f / 64.f);
    const float c = v - mean;
    const float var = wave_sum64(c * c) * (1.f / 64.f);
    const float xx = c * rsqrtf(var + EPS_) * (isq ? qnw[lane] : knw[lane]);
    const float part = __shfl_xor(xx, 32);
    const float rot = (lane < 32) ? -part : part;
    const size_t ci = (size_t)(b * N_ + n) * D_ + lane;
    const float res = (xx * cosb[ci] + rot * sinb[ci]) * oscale;
    (isq ? Qb : Kb)[((size_t)(b * H_ + h) * N_ + n) * D_ + lane] = f2bf(res);
  } else if (blk < 33792) {
    const int blk2 = blk - 32768;
    const int n0 = (blk2 & 31) * 64, h = (blk2 >> 5) & 15, b = blk2 >> 9;
    #pragma unroll
    for (int it = 0; it < 4; ++it) {
      int idx = tid + it * 256;
      int r = idx >> 4, d4 = (idx & 15) << 2;
      float4 v = *(const float4*)(kv + (size_t)(b * N_ + n0 + r) * (2*C_) + h*128 + 64 + d4);
      Vs[d4+0][r] = f2bf(v.x); Vs[d4+1][r] = f2bf(v.y);
      Vs[d4+2][r] = f2bf(v.z); Vs[d4+3][r] = f2bf(v.w);
    }
    __syncthreads();
    typedef unsigned short u16x8 __attribute__((ext_vector_type(8)));
    #pragma unroll
    for (int it = 0; it < 2; ++it) {
      int c = tid + it * 256;
      int d = c >> 3, cb = (c & 7) << 3;
      u16x8 v = *(const u16x8*)&Vs[d][cb];
      *(u16x8*)(Vtp + ((size_t)(b*H_+h)*D_ + d) * N_ + n0 + cb) = v;
    }
  } else {
    const int e = ((blk - 33792) * 256 + tid) << 2;
    pack_one(Wo, wop, e);
  }
}

// ---------- bf16 MFMA flash attention, KVBLK=128, exp2 domain, defer-max ----------
__global__ __launch_bounds__(256) void flash_bf16(
    const unsigned short* __restrict__ Qb, const unsigned short* __restrict__ Kb,
    const unsigned short* __restrict__ Vt, const float* __restrict__ qg,
    unsigned short* __restrict__ gp)
{
  const int b = blockIdx.z, h = blockIdx.y, q0 = blockIdx.x * 64;
  const int tid = threadIdx.x, lane = tid & 63, wave = tid >> 6;
  __shared__ __align__(16) unsigned short Ks[128 * 64];   // 128 kv-rows x 128B (swz slot^row&7)
  __shared__ __align__(16) unsigned short Vss[64 * 128];  // 64 d-rows x 256B (swz slot^row&7)
  __shared__ __align__(16) __bf16 Ps[4][16][136];         // per-wave P, 272B stride
  const int bh = b * H_ + h;

  b16x8 qf0, qf1;
  {
    const unsigned short* Qrow = Qb + ((size_t)bh * N_ + q0 + wave*16 + (lane & 15)) * D_;
    qf0 = *(const b16x8*)(Qrow + ((lane >> 4) << 3));
    qf1 = *(const b16x8*)(Qrow + 32 + ((lane >> 4) << 3));
  }

  f32x4 acc[4];
  float mreg[4], lreg[4];
  #pragma unroll
  for (int r = 0; r < 4; ++r) {
    mreg[r] = -1e30f; lreg[r] = 0.f;
    acc[r] = (f32x4){0.f, 0.f, 0.f, 0.f};
  }

  const unsigned short* Kbh  = Kb + (size_t)bh * N_ * D_;
  const unsigned short* Vtbh = Vt + (size_t)bh * D_ * N_;
  const int swzK = ((lane & 7) ^ (lane >> 3)) << 4;
  const int vr = lane >> 4;
  const int cb0 = (lane >> 4) << 4;

  for (int j0 = 0; j0 < N_; j0 += 128) {
    // stage K (128x128B) + V (64x256B), pre-swizzled source, linear LDS dest
    #pragma unroll
    for (int i = 0; i < 4; ++i) {
      const int g = wave * 4 + i;
      const char* ksrc = (const char*)(Kbh + (size_t)(j0 + g * 8) * D_) + (lane >> 3) * 128 + swzK;
      __builtin_amdgcn_global_load_lds(
          (const __attribute__((address_space(1))) void*)ksrc,
          (__attribute__((address_space(3))) void*)((char*)Ks + g * 1024), 16, 0, 0);
      const int dv = g * 4 + vr;
      const char* vsrc = (const char*)(Vtbh + (size_t)dv * N_ + j0) + (((lane & 15) ^ (dv & 7)) << 4);
      __builtin_amdgcn_global_load_lds(
          (const __attribute__((address_space(1))) void*)vsrc,
          (__attribute__((address_space(3))) void*)((char*)Vss + g * 1024), 16, 0, 0);
    }
    __syncthreads();

    // QK^T: S[16q x 128kv] per wave (log2 units; scale folded into Q)
    f32x4 sacc[8];
    #pragma unroll
    for (int t = 0; t < 8; ++t) {
      sacc[t] = (f32x4){0.f, 0.f, 0.f, 0.f};
      const int krow = t * 16 + (lane & 15);
      const char* kb = (const char*)Ks + krow * 128;
      const int f = (krow & 7) << 4;
      b16x8 kf0 = *(const b16x8*)(kb + (cb0 ^ f));
      b16x8 kf1 = *(const b16x8*)(kb + ((64 + cb0) ^ f));
      sacc[t] = __builtin_amdgcn_mfma_f32_16x16x32_bf16(qf0, kf0, sacc[t], 0, 0, 0);
      sacc[t] = __builtin_amdgcn_mfma_f32_16x16x32_bf16(qf1, kf1, sacc[t], 0, 0, 0);
    }

    // tile max per row
    float mt[4];
    #pragma unroll
    for (int r = 0; r < 4; ++r) {
      float v0 = fmaxf(fmaxf(sacc[0][r], sacc[1][r]), fmaxf(sacc[2][r], sacc[3][r]));
      float v1 = fmaxf(fmaxf(sacc[4][r], sacc[5][r]), fmaxf(sacc[6][r], sacc[7][r]));
      float v = fmaxf(v0, v1);
      #pragma unroll
      for (int off = 1; off < 16; off <<= 1) v = fmaxf(v, __shfl_xor(v, off));
      mt[r] = v;
    }
    // defer-max (THR=8 log2 units -> P <= 256)
    const bool defer = (mt[0] <= mreg[0] + 8.f) && (mt[1] <= mreg[1] + 8.f) &&
                       (mt[2] <= mreg[2] + 8.f) && (mt[3] <= mreg[3] + 8.f);
    if (!__all(defer)) {
      #pragma unroll
      for (int r = 0; r < 4; ++r) {
        const float mn = fmaxf(mreg[r], mt[r]);
        const float al = __builtin_amdgcn_exp2f(mreg[r] - mn);
        lreg[r] *= al; mreg[r] = mn;
        acc[0][r] *= al; acc[1][r] *= al; acc[2][r] *= al; acc[3][r] *= al;
      }
    }
    // P = exp2(S - m), bf16 store to own-wave Ps
    #pragma unroll
    for (int r = 0; r < 4; ++r) {
      float rs = 0.f;
      __bf16* pw = &Ps[wave][((lane >> 4) << 2) + r][lane & 15];
      #pragma unroll
      for (int t = 0; t < 8; ++t) {
        const float p = __builtin_amdgcn_exp2f(sacc[t][r] - mreg[r]);
        rs += p;
        pw[t * 16] = (__bf16)p;
      }
      #pragma unroll
      for (int off = 1; off < 16; off <<= 1) rs += __shfl_xor(rs, off);
      lreg[r] += rs;
    }

    // PV: O[16q x 64d] += P @ V
    b16x8 pf[4];
    #pragma unroll
    for (int c = 0; c < 4; ++c)
      pf[c] = *(const b16x8*)(&Ps[wave][lane & 15][c * 32 + ((lane >> 4) << 3)]);
    #pragma unroll
    for (int dt = 0; dt < 4; ++dt) {
      const int vrow = dt * 16 + (lane & 15);
      const char* vb = (const char*)Vss + vrow * 256;
      const int fv = (vrow & 7) << 4;
      #pragma unroll
      for (int c = 0; c < 4; ++c) {
        b16x8 vf = *(const b16x8*)(vb + ((c * 64 + cb0) ^ fv));
        acc[dt] = __builtin_amdgcn_mfma_f32_16x16x32_bf16(pf[c], vf, acc[dt], 0, 0, 0);
      }
    }
    __syncthreads();
  }

  // epilogue: normalize, sigmoid gate, write hi/lo-packed gp (B*N, 2048)
  #pragma unroll
  for (int r = 0; r < 4; ++r) {
    const int row = ((lane >> 4) << 2) + r;
    const int q = q0 + wave*16 + row;
    const float inv = 1.f / lreg[r];
    const size_t rowbase = (size_t)(b*N_ + q) * PK_;
    #pragma unroll
    for (int dt = 0; dt < 4; ++dt) {
      const int d = (dt << 4) + (lane & 15);
      const float o = acc[dt][r] * inv;
      const float gate = qg[(size_t)(b*N_ + q) * (2*C_) + h*128 + 64 + d];
      const float sg = 1.f / (1.f + __expf(-gate));
      const float val = o * sg;
      const int k = h*64 + d;
      unsigned short* p = gp + rowbase + ((k >> 5) << 6) + (k & 31);
      const unsigned short hi = f2bf(val);
      p[0]  = hi;
      p[32] = f2bf(val - bf2f(hi));
    }
  }
}

extern "C" void kernel_launch(void* const* d_in, const int* in_sizes, int n_in,
                              void* d_out, int out_size, void* d_ws, size_t ws_size,
                              hipStream_t stream) {
  const float* x    = (const float*)d_in[0];
  const float* ctx  = (const float*)d_in[1];
  const float* cosb = (const float*)d_in[2];
  const float* sinb = (const float*)d_in[3];
  const float* Wq   = (const float*)d_in[4];
  const float* Wkv  = (const float*)d_in[5];
  const float* Wo   = (const float*)d_in[6];
  const float* bo   = (const float*)d_in[7];
  const float* qnw  = (const float*)d_in[8];
  const float* knw  = (const float*)d_in[9];
  float* out = (float*)d_out;

  char* ws = (char*)d_ws;
  float* qg           = (float*)(ws);                              // 32M @0
  float* kv           = (float*)(ws + (size_t)33554432);           // 32M @32M
  unsigned short* gpk = (unsigned short*)(ws + (size_t)33554432);  // 16M @32M (after kv)
  unsigned short* cp  = (unsigned short*)(ws + (size_t)67108864);  // 16M @64M
  unsigned short* Qb  = (unsigned short*)(ws + (size_t)67108864);  // 8M  @64M (after cp)
  unsigned short* Kb  = (unsigned short*)(ws + (size_t)75497472);  // 8M  @72M (after cp)
  unsigned short* xp  = (unsigned short*)(ws + (size_t)83886080);  // 16M @80M
  unsigned short* wkvp= (unsigned short*)(ws + (size_t)83886080);  // 8M  @80M (after xp)
  unsigned short* Vt  = (unsigned short*)(ws + (size_t)83886080);  // 8M  @80M (after wkvp)
  unsigned short* wop = (unsigned short*)(ws + (size_t)92274688);  // 4M  @88M
  unsigned short* wqp = (unsigned short*)(ws + (size_t)100663296); // 8M  @96M

  const dim3 blk(256);
  pack3<<<dim3(10240), blk, 0, stream>>>(x, Wq, ctx, xp, wqp, cp);
  gemm_nt_hilo<<<dim3(512), blk, 0, stream>>>(xp, wqp, qg, 4096, 2048, nullptr);
  pack_hilo<<<dim3(2048), blk, 0, stream>>>(Wkv, wkvp, 2097152);
  gemm_nt_hilo<<<dim3(512), blk, 0, stream>>>(cp, wkvp, kv, 4096, 2048, nullptr);
  prep_all<<<dim3(34816), blk, 0, stream>>>(qg, kv, cosb, sinb, qnw, knw, Wo, Qb, Kb, Vt, wop);
  flash_bf16<<<dim3(32, 16, 2), blk, 0, stream>>>(Qb, Kb, Vt, qg, gpk);
  gemm_nt_hilo<<<dim3(256), blk, 0, stream>>>(gpk, wop, out, 4096, 1024, bo);
}

// Round 5
// 240.877 us; speedup vs baseline: 5.2626x; 1.1877x over previous
//
#include <hip/hip_runtime.h>
#include <cstdint>
#include <cstddef>

// CrossAttention: split-bf16 (hi/lo, 3-MFMA) projection GEMMs with FUSED
// norm/rope/gate/V-transpose epilogues + bf16 MFMA flash attention with
// swapped-operand QK^T (lane-local softmax rows, b64 P stores).
// Launches: pack_all | gemm<1> (x@Wq.T -> Qb,gate) | gemm<2> (ctx@Wkv.T -> Kb,Vt)
//           | flash -> gpk | gemm<0> (g@Wo.T + bo -> out)   (5)
// ws (92MiB): Qb 8M@0 | Kb 8M@8M | Vt 8M@16M | gate 16M@24M | xp->gpk 16M@40M
//             | cp 16M@56M | wqp 8M@72M | wkvp 8M@80M | wop 4M@88M

#define B_ 2
#define N_ 2048
#define C_ 1024
#define H_ 16
#define D_ 64
#define K_ 1024
#define PK_ 2048
#define EPS_ 1e-6f
#define LOG2E_ 1.44269504088896f

typedef __bf16 b16x8 __attribute__((ext_vector_type(8)));
typedef float f32x4 __attribute__((ext_vector_type(4)));

__device__ __forceinline__ unsigned short f2bf(float f) {
  union { float f; unsigned u; } a; a.f = f;
  unsigned r = a.u + 0x7FFFu + ((a.u >> 16) & 1u);
  return (unsigned short)(r >> 16);
}
__device__ __forceinline__ float bf2f(unsigned short u) {
  union { unsigned u; float f; } a; a.u = ((unsigned)u) << 16; return a.f;
}

// pack 4 consecutive fp32 (row-width 1024) into hi/lo bf16 chunks (row-width 2048)
__device__ __forceinline__ void pack_one(const float* __restrict__ src,
                                         unsigned short* __restrict__ dst, int e) {
  float4 v = *(const float4*)(src + e);
  const int r = e >> 10, k = e & 1023;
  unsigned short* p = dst + ((size_t)r << 11) + ((k >> 5) << 6) + (k & 31);
  const unsigned short h0 = f2bf(v.x), h1 = f2bf(v.y), h2 = f2bf(v.z), h3 = f2bf(v.w);
  *(ushort4*)p = make_ushort4(h0, h1, h2, h3);
  *(ushort4*)(p + 32) = make_ushort4(f2bf(v.x - bf2f(h0)), f2bf(v.y - bf2f(h1)),
                                     f2bf(v.z - bf2f(h2)), f2bf(v.w - bf2f(h3)));
}

// fused pack of x(4M) | Wq(2M) | ctx(4M) | Wkv(2M) | Wo(1M) floats
__global__ __launch_bounds__(256) void pack_all(
    const float* __restrict__ x, const float* __restrict__ Wq,
    const float* __restrict__ ctx, const float* __restrict__ Wkv,
    const float* __restrict__ Wo,
    unsigned short* __restrict__ xp, unsigned short* __restrict__ wqp,
    unsigned short* __restrict__ cp, unsigned short* __restrict__ wkvp,
    unsigned short* __restrict__ wop)
{
  const int e = (blockIdx.x * 256 + threadIdx.x) << 2;
  if (e < 4194304)       pack_one(x,   xp,  e);
  else if (e < 6291456)  pack_one(Wq,  wqp, e - 4194304);
  else if (e < 10485760) pack_one(ctx, cp,  e - 6291456);
  else if (e < 12582912) pack_one(Wkv, wkvp, e - 10485760);
  else                   pack_one(Wo,  wop, e - 12582912);
}

// ---------- split-bf16 GEMM NT with fused epilogues ----------
// MODE 0: Cm = A@B.T + bias (fp32).
// MODE 1: q-proj: cols d<64 -> zmRMSNorm+RoPE -> nOut bf16 (B,H,N,D) *oscale;
//         cols d>=64 -> gate fp32 (B*N, C) in vOut.
// MODE 2: kv-proj: cols d<64 -> norm+rope -> nOut (Kb); d>=64 -> Vt bf16 (B,H,D,N).
template<int MODE>
__global__ __launch_bounds__(256) void gemm_nt_hilo(
    const unsigned short* __restrict__ Ap, const unsigned short* __restrict__ Bp,
    float* __restrict__ Cm, int M, int N, const float* __restrict__ bias,
    const float* __restrict__ cosb, const float* __restrict__ sinb,
    const float* __restrict__ nw, unsigned short* __restrict__ nOut,
    void* __restrict__ vOut, float oscale)
{
  __shared__ __align__(16) unsigned short As[128 * 64];
  __shared__ __align__(16) unsigned short Bs[128 * 64];
  const int tid = threadIdx.x, lane = tid & 63, wave = tid >> 6;

  const int nwg = gridDim.x, id = blockIdx.x;
  const int swz = (id & 7) * (nwg >> 3) + (id >> 3);
  const int nbn = N >> 7;
  const int bm = (swz / nbn) << 7, bn = (swz % nbn) << 7;
  const int wm = (wave >> 1) << 6, wn = (wave & 1) << 6;

  const int srow = lane >> 3;
  const int sslot = (lane & 7) ^ srow;
  const size_t rbytes = (size_t)K_ * 4;
  const char* aSrc = (const char*)Ap + (size_t)(bm + srow) * rbytes + (sslot << 4);
  const char* bSrc = (const char*)Bp + (size_t)(bn + srow) * rbytes + (sslot << 4);

  f32x4 acc[4][4];
  #pragma unroll
  for (int i = 0; i < 4; ++i)
    #pragma unroll
    for (int j = 0; j < 4; ++j) acc[i][j] = (f32x4){0.f, 0.f, 0.f, 0.f};

  const int fr = lane & 15, fs = lane >> 4;
  const int hoff = (fs ^ (fr & 7)) << 4;

  for (int ks = 0; ks < K_ / 32; ++ks) {
    const size_t ko = (size_t)ks << 7;
    #pragma unroll
    for (int i = 0; i < 4; ++i) {
      const int g = (wave << 2) + i;
      __builtin_amdgcn_global_load_lds(
          (const __attribute__((address_space(1))) void*)(aSrc + (size_t)(g << 3) * rbytes + ko),
          (__attribute__((address_space(3))) void*)((char*)As + (g << 10)), 16, 0, 0);
      __builtin_amdgcn_global_load_lds(
          (const __attribute__((address_space(1))) void*)(bSrc + (size_t)(g << 3) * rbytes + ko),
          (__attribute__((address_space(3))) void*)((char*)Bs + (g << 10)), 16, 0, 0);
    }
    __syncthreads();

    b16x8 ah[4], al[4], bh[4], bl[4];
    #pragma unroll
    for (int t = 0; t < 4; ++t) {
      const char* pa = (const char*)As + ((wm + (t << 4) + fr) << 7);
      ah[t] = *(const b16x8*)(pa + hoff);
      al[t] = *(const b16x8*)(pa + (hoff ^ 64));
      const char* pb = (const char*)Bs + ((wn + (t << 4) + fr) << 7);
      bh[t] = *(const b16x8*)(pb + hoff);
      bl[t] = *(const b16x8*)(pb + (hoff ^ 64));
    }
    #pragma unroll
    for (int mi = 0; mi < 4; ++mi)
      #pragma unroll
      for (int ni = 0; ni < 4; ++ni) {
        acc[mi][ni] = __builtin_amdgcn_mfma_f32_16x16x32_bf16(ah[mi], bh[ni], acc[mi][ni], 0, 0, 0);
        acc[mi][ni] = __builtin_amdgcn_mfma_f32_16x16x32_bf16(al[mi], bh[ni], acc[mi][ni], 0, 0, 0);
        acc[mi][ni] = __builtin_amdgcn_mfma_f32_16x16x32_bf16(ah[mi], bl[ni], acc[mi][ni], 0, 0, 0);
      }
    __syncthreads();
  }

  const int g = lane >> 4;
  if constexpr (MODE == 0) {
    const int rbase = g << 2;
    #pragma unroll
    for (int mi = 0; mi < 4; ++mi)
      #pragma unroll
      for (int ni = 0; ni < 4; ++ni) {
        const int n = bn + wn + (ni << 4) + fr;
        const float badd = bias ? bias[n] : 0.f;
        #pragma unroll
        for (int r = 0; r < 4; ++r) {
          const int m = bm + wm + (mi << 4) + rbase + r;
          Cm[(size_t)m * N + n] = acc[mi][ni][r] + badd;
        }
      }
  } else {
    const int h = bn >> 7;
    if (wn == 0) {
      // zero-mean RMSNorm + RoPE -> bf16 nOut (B,H,N,D)
      float wv[4];
      #pragma unroll
      for (int ni = 0; ni < 4; ++ni) wv[ni] = nw[(ni << 4) + fr];
      #pragma unroll
      for (int mi = 0; mi < 4; ++mi) {
        #pragma unroll
        for (int r = 0; r < 4; ++r) {
          const int t = bm + wm + (mi << 4) + (g << 2) + r;
          float v0 = acc[mi][0][r], v1 = acc[mi][1][r];
          float v2 = acc[mi][2][r], v3 = acc[mi][3][r];
          float s = (v0 + v1) + (v2 + v3);
          #pragma unroll
          for (int off = 1; off < 16; off <<= 1) s += __shfl_xor(s, off);
          const float mean = s * (1.f / 64.f);
          v0 -= mean; v1 -= mean; v2 -= mean; v3 -= mean;
          float s2 = (v0*v0 + v1*v1) + (v2*v2 + v3*v3);
          #pragma unroll
          for (int off = 1; off < 16; off <<= 1) s2 += __shfl_xor(s2, off);
          const float rq = rsqrtf(s2 * (1.f / 64.f) + EPS_);
          const float x0 = v0 * rq * wv[0], x1 = v1 * rq * wv[1];
          const float x2 = v2 * rq * wv[2], x3 = v3 * rq * wv[3];
          const float* cr = cosb + (size_t)t * 64;
          const float* sr = sinb + (size_t)t * 64;
          const float o0 = x0 * cr[fr]      - x2 * sr[fr];
          const float o1 = x1 * cr[16+fr]   - x3 * sr[16+fr];
          const float o2 = x2 * cr[32+fr]   + x0 * sr[32+fr];
          const float o3 = x3 * cr[48+fr]   + x1 * sr[48+fr];
          unsigned short* dp = nOut + (((size_t)((t >> 11) * H_ + h)) * N_ + (t & 2047)) * 64;
          dp[fr]      = f2bf(o0 * oscale);
          dp[16 + fr] = f2bf(o1 * oscale);
          dp[32 + fr] = f2bf(o2 * oscale);
          dp[48 + fr] = f2bf(o3 * oscale);
        }
      }
    } else if constexpr (MODE == 1) {
      // gate fp32 -> (B*N, C)
      float* gb = (float*)vOut;
      #pragma unroll
      for (int mi = 0; mi < 4; ++mi)
        #pragma unroll
        for (int r = 0; r < 4; ++r) {
          const int t = bm + wm + (mi << 4) + (g << 2) + r;
          float* gp = gb + (size_t)t * C_ + h * 64;
          #pragma unroll
          for (int ni = 0; ni < 4; ++ni) gp[(ni << 4) + fr] = acc[mi][ni][r];
        }
    } else {
      // V -> bf16 transposed (B,H,D,N)
      unsigned short* vt = (unsigned short*)vOut;
      #pragma unroll
      for (int mi = 0; mi < 4; ++mi) {
        const int t0 = bm + wm + (mi << 4) + (g << 2);
        const int bb = t0 >> 11, n0 = t0 & 2047;
        #pragma unroll
        for (int ni = 0; ni < 4; ++ni) {
          const int dv = (ni << 4) + fr;
          ushort4 pk = make_ushort4(f2bf(acc[mi][ni][0]), f2bf(acc[mi][ni][1]),
                                    f2bf(acc[mi][ni][2]), f2bf(acc[mi][ni][3]));
          *(ushort4*)(vt + ((size_t)(bb * H_ + h) * 64 + dv) * N_ + n0) = pk;
        }
      }
    }
  }
}

// ---------- bf16 MFMA flash attention: swapped QK^T, lane-local softmax ----------
__global__ __launch_bounds__(256) void flash_bf16(
    const unsigned short* __restrict__ Qb, const unsigned short* __restrict__ Kb,
    const unsigned short* __restrict__ Vt, const float* __restrict__ gateb,
    unsigned short* __restrict__ gp)
{
  const int b = blockIdx.z, h = blockIdx.y, q0 = blockIdx.x * 64;
  const int tid = threadIdx.x, lane = tid & 63, wave = tid >> 6;
  __shared__ __align__(16) unsigned short Ks[128 * 64];   // 128 kv-rows x 128B (swz)
  __shared__ __align__(16) unsigned short Vss[64 * 128];  // 64 d-rows x 256B (swz)
  __shared__ __align__(16) __bf16 Ps[4][16][136];         // per-wave P[q][kv], 272B rows
  const int bh = b * H_ + h;
  const int g = lane >> 4, fr = lane & 15;

  b16x8 qf0, qf1;
  {
    const unsigned short* Qrow = Qb + ((size_t)bh * N_ + q0 + wave*16 + fr) * D_;
    qf0 = *(const b16x8*)(Qrow + (g << 3));
    qf1 = *(const b16x8*)(Qrow + 32 + (g << 3));
  }

  f32x4 acc[4];
  #pragma unroll
  for (int r = 0; r < 4; ++r) acc[r] = (f32x4){0.f, 0.f, 0.f, 0.f};
  float mreg = -1e30f, lreg = 0.f;   // per-lane state for q = fr

  const unsigned short* Kbh  = Kb + (size_t)bh * N_ * D_;
  const unsigned short* Vtbh = Vt + (size_t)bh * D_ * N_;
  const int swzK = ((lane & 7) ^ (lane >> 3)) << 4;
  __bf16* Pw = &Ps[wave][0][0] + fr * 136;   // this lane's q-row

  for (int j0 = 0; j0 < N_; j0 += 128) {
    // stage K (128x128B rows) + V (64x256B rows), pre-swizzled source, linear dest
    #pragma unroll
    for (int i = 0; i < 4; ++i) {
      const int gg = wave * 4 + i;
      const char* ksrc = (const char*)(Kbh + (size_t)(j0 + gg * 8) * D_) + (lane >> 3) * 128 + swzK;
      __builtin_amdgcn_global_load_lds(
          (const __attribute__((address_space(1))) void*)ksrc,
          (__attribute__((address_space(3))) void*)((char*)Ks + gg * 1024), 16, 0, 0);
      const int dv = gg * 4 + g;
      const char* vsrc = (const char*)(Vtbh + (size_t)dv * N_ + j0) + ((fr ^ (dv & 7)) << 4);
      __builtin_amdgcn_global_load_lds(
          (const __attribute__((address_space(1))) void*)vsrc,
          (__attribute__((address_space(3))) void*)((char*)Vss + gg * 1024), 16, 0, 0);
    }
    __syncthreads();

    // QK^T swapped: S rows = kv, cols = q -> lane holds q=fr, kv = t*16+g*4+r
    f32x4 sacc[8];
    const int cb0 = g << 4;
    #pragma unroll
    for (int t = 0; t < 8; ++t) {
      sacc[t] = (f32x4){0.f, 0.f, 0.f, 0.f};
      const int krow = t * 16 + fr;
      const char* kb = (const char*)Ks + krow * 128;
      const int f = (krow & 7) << 4;
      b16x8 kf0 = *(const b16x8*)(kb + (cb0 ^ f));
      b16x8 kf1 = *(const b16x8*)(kb + ((64 + cb0) ^ f));
      sacc[t] = __builtin_amdgcn_mfma_f32_16x16x32_bf16(kf0, qf0, sacc[t], 0, 0, 0);
      sacc[t] = __builtin_amdgcn_mfma_f32_16x16x32_bf16(kf1, qf1, sacc[t], 0, 0, 0);
    }

    // lane-local tile max over 32 values + 2 cross-group shuffles
    float mt = sacc[0][0];
    #pragma unroll
    for (int t = 0; t < 8; ++t)
      #pragma unroll
      for (int r = 0; r < 4; ++r) mt = fmaxf(mt, sacc[t][r]);
    mt = fmaxf(mt, __shfl_xor(mt, 16));
    mt = fmaxf(mt, __shfl_xor(mt, 32));
    // defer-max (THR=8 log2 units -> P <= 256)
    if (!__all(mt <= mreg + 8.f)) {
      const float mn = fmaxf(mreg, mt);
      const float al = __builtin_amdgcn_exp2f(mreg - mn);
      mreg = mn; lreg *= al;
      #pragma unroll
      for (int r = 0; r < 4; ++r) {
        const float alr = __shfl(al, (g << 2) + r);
        acc[0][r] *= alr; acc[1][r] *= alr; acc[2][r] *= alr; acc[3][r] *= alr;
      }
    }
    // P = exp2(S - m); b64 stores of 4 consecutive kv
    float rs = 0.f;
    #pragma unroll
    for (int t = 0; t < 8; ++t) {
      union { __bf16 hb[4]; ushort4 u4; } pk;
      #pragma unroll
      for (int r = 0; r < 4; ++r) {
        const float p = __builtin_amdgcn_exp2f(sacc[t][r] - mreg);
        rs += p;
        pk.hb[r] = (__bf16)p;
      }
      *(ushort4*)(Pw + t * 16 + (g << 2)) = pk.u4;
    }
    rs += __shfl_xor(rs, 16);
    rs += __shfl_xor(rs, 32);
    lreg += rs;

    // PV: O[16q x 64d] += P @ V  (A=P rows=q, B=V cols=d)
    b16x8 pf[4];
    #pragma unroll
    for (int c = 0; c < 4; ++c)
      pf[c] = *(const b16x8*)(Pw + c * 32 + (g << 3));
    #pragma unroll
    for (int dt = 0; dt < 4; ++dt) {
      const int vrow = dt * 16 + fr;
      const char* vb = (const char*)Vss + vrow * 256;
      const int fv = (vrow & 7) << 4;
      #pragma unroll
      for (int c = 0; c < 4; ++c) {
        b16x8 vf = *(const b16x8*)(vb + ((c * 64 + cb0) ^ fv));
        acc[dt] = __builtin_amdgcn_mfma_f32_16x16x32_bf16(pf[c], vf, acc[dt], 0, 0, 0);
      }
    }
    __syncthreads();
  }

  // epilogue: normalize, sigmoid gate, write hi/lo-packed gp (B*N, 2048)
  #pragma unroll
  for (int r = 0; r < 4; ++r) {
    const float lr = __shfl(lreg, (g << 2) + r);
    const float inv = 1.f / lr;
    const int q = q0 + wave * 16 + (g << 2) + r;
    const size_t rowbase = (size_t)(b * N_ + q) * PK_;
    #pragma unroll
    for (int dt = 0; dt < 4; ++dt) {
      const int d = (dt << 4) + fr;
      const float o = acc[dt][r] * inv;
      const float gate = gateb[(size_t)(b * N_ + q) * C_ + h * 64 + d];
      const float sg = 1.f / (1.f + __expf(-gate));
      const float val = o * sg;
      const int k = h * 64 + d;
      unsigned short* p = gp + rowbase + ((k >> 5) << 6) + (k & 31);
      const unsigned short hi = f2bf(val);
      p[0]  = hi;
      p[32] = f2bf(val - bf2f(hi));
    }
  }
}

extern "C" void kernel_launch(void* const* d_in, const int* in_sizes, int n_in,
                              void* d_out, int out_size, void* d_ws, size_t ws_size,
                              hipStream_t stream) {
  const float* x    = (const float*)d_in[0];
  const float* ctx  = (const float*)d_in[1];
  const float* cosb = (const float*)d_in[2];
  const float* sinb = (const float*)d_in[3];
  const float* Wq   = (const float*)d_in[4];
  const float* Wkv  = (const float*)d_in[5];
  const float* Wo   = (const float*)d_in[6];
  const float* bo   = (const float*)d_in[7];
  const float* qnw  = (const float*)d_in[8];
  const float* knw  = (const float*)d_in[9];
  float* out = (float*)d_out;

  char* ws = (char*)d_ws;
  unsigned short* Qb   = (unsigned short*)(ws);                    // 8M  @0
  unsigned short* Kb   = (unsigned short*)(ws + (size_t)8388608);  // 8M  @8M
  unsigned short* Vt   = (unsigned short*)(ws + (size_t)16777216); // 8M  @16M
  float*          gate = (float*)(ws + (size_t)25165824);          // 16M @24M
  unsigned short* xp   = (unsigned short*)(ws + (size_t)41943040); // 16M @40M
  unsigned short* gpk  = (unsigned short*)(ws + (size_t)41943040); // 16M @40M (after gemm1)
  unsigned short* cp   = (unsigned short*)(ws + (size_t)58720256); // 16M @56M
  unsigned short* wqp  = (unsigned short*)(ws + (size_t)75497472); // 8M  @72M
  unsigned short* wkvp = (unsigned short*)(ws + (size_t)83886080); // 8M  @80M
  unsigned short* wop  = (unsigned short*)(ws + (size_t)92274688); // 4M  @88M

  const dim3 blk(256);
  pack_all<<<dim3(13312), blk, 0, stream>>>(x, Wq, ctx, Wkv, Wo, xp, wqp, cp, wkvp, wop);
  gemm_nt_hilo<1><<<dim3(512), blk, 0, stream>>>(xp, wqp, nullptr, 4096, 2048, nullptr,
                                                 cosb, sinb, qnw, Qb, gate, 0.125f * LOG2E_);
  gemm_nt_hilo<2><<<dim3(512), blk, 0, stream>>>(cp, wkvp, nullptr, 4096, 2048, nullptr,
                                                 cosb, sinb, knw, Kb, Vt, 1.0f);
  flash_bf16<<<dim3(32, 16, 2), blk, 0, stream>>>(Qb, Kb, Vt, gate, gpk);
  gemm_nt_hilo<0><<<dim3(256), blk, 0, stream>>>(gpk, wop, out, 4096, 1024, bo,
                                                 nullptr, nullptr, nullptr, nullptr, nullptr, 1.0f);
}

// Round 6
// 184.853 us; speedup vs baseline: 6.8576x; 1.3031x over previous
//
#include <hip/hip_runtime.h>
#include <cstdint>
#include <cstddef>

// CrossAttention r6: SINGLE-bf16 projection GEMMs (norm/softmax smooth the
// rounding; outputs re-rounded to bf16 anyway) with fused norm/rope/gate/Vt
// epilogues; split-bf16 (3-MFMA) kept ONLY for the output GEMM; flash attn
// with swapped QK^T and STATIC-max softmax (|S|<=11.54 by Cauchy-Schwarz).
// Launches: pack_all | gemm_bf16<1> | gemm_bf16<2> | flash | gemm_hilo  (5)
// ws (84MiB): Qb 8M@0 | Kb 8M@8M | Vt 8M@16M | gate 16M@24M | gpk 16M@40M
//             | xb 8M@56M | cb 8M@64M | wqb 4M@72M | wkvb 4M@76M | wop 4M@80M

#define B_ 2
#define N_ 2048
#define C_ 1024
#define H_ 16
#define D_ 64
#define K_ 1024
#define PK_ 2048
#define EPS_ 1e-6f
#define LOG2E_ 1.44269504088896f
#define SMAX_ 12.0f

typedef __bf16 b16x8 __attribute__((ext_vector_type(8)));
typedef float f32x4 __attribute__((ext_vector_type(4)));

__device__ __forceinline__ unsigned short f2bf(float f) {
  union { float f; unsigned u; } a; a.f = f;
  unsigned r = a.u + 0x7FFFu + ((a.u >> 16) & 1u);
  return (unsigned short)(r >> 16);
}
__device__ __forceinline__ float bf2f(unsigned short u) {
  union { unsigned u; float f; } a; a.u = ((unsigned)u) << 16; return a.f;
}

// plain bf16 cast of 4 consecutive floats (row layout preserved)
__device__ __forceinline__ void cast_one(const float* __restrict__ src,
                                         unsigned short* __restrict__ dst, int e) {
  float4 v = *(const float4*)(src + e);
  *(ushort4*)(dst + e) = make_ushort4(f2bf(v.x), f2bf(v.y), f2bf(v.z), f2bf(v.w));
}

// hi/lo pack (row width 1024 -> 2048, 32-elem chunk interleave) for Wo only
__device__ __forceinline__ void pack_one(const float* __restrict__ src,
                                         unsigned short* __restrict__ dst, int e) {
  float4 v = *(const float4*)(src + e);
  const int r = e >> 10, k = e & 1023;
  unsigned short* p = dst + ((size_t)r << 11) + ((k >> 5) << 6) + (k & 31);
  const unsigned short h0 = f2bf(v.x), h1 = f2bf(v.y), h2 = f2bf(v.z), h3 = f2bf(v.w);
  *(ushort4*)p = make_ushort4(h0, h1, h2, h3);
  *(ushort4*)(p + 32) = make_ushort4(f2bf(v.x - bf2f(h0)), f2bf(v.y - bf2f(h1)),
                                     f2bf(v.z - bf2f(h2)), f2bf(v.w - bf2f(h3)));
}

// fused prep: cast x | Wq | ctx | Wkv to bf16; hi/lo-pack Wo
__global__ __launch_bounds__(256) void pack_all(
    const float* __restrict__ x, const float* __restrict__ Wq,
    const float* __restrict__ ctx, const float* __restrict__ Wkv,
    const float* __restrict__ Wo,
    unsigned short* __restrict__ xb, unsigned short* __restrict__ wqb,
    unsigned short* __restrict__ cb, unsigned short* __restrict__ wkvb,
    unsigned short* __restrict__ wop)
{
  const int e = (blockIdx.x * 256 + threadIdx.x) << 2;
  if (e < 4194304)       cast_one(x,   xb,  e);
  else if (e < 6291456)  cast_one(Wq,  wqb, e - 4194304);
  else if (e < 10485760) cast_one(ctx, cb,  e - 6291456);
  else if (e < 12582912) cast_one(Wkv, wkvb, e - 10485760);
  else                   pack_one(Wo,  wop, e - 12582912);
}

// ---------- single-bf16 GEMM NT with fused epilogues ----------
// A (M,K) bf16 row-major, B (N,K) bf16 row-major. 128x128 tile, BK=64,
// 4 waves (2x2 of 64x64). MODE 1: q-proj (norm+rope->Qb, gate fp32).
// MODE 2: kv-proj (norm+rope->Kb, V->Vt transposed bf16).
template<int MODE>
__global__ __launch_bounds__(256) void gemm_nt_bf16(
    const unsigned short* __restrict__ Ap, const unsigned short* __restrict__ Bp,
    int M, int N,
    const float* __restrict__ cosb, const float* __restrict__ sinb,
    const float* __restrict__ nw, unsigned short* __restrict__ nOut,
    void* __restrict__ vOut, float oscale)
{
  __shared__ __align__(16) unsigned short As[128 * 64];  // 128 rows x 128B (swz)
  __shared__ __align__(16) unsigned short Bs[128 * 64];
  const int tid = threadIdx.x, lane = tid & 63, wave = tid >> 6;

  const int nwg = gridDim.x, id = blockIdx.x;
  const int swz = (id & 7) * (nwg >> 3) + (id >> 3);
  const int nbn = N >> 7;
  const int bm = (swz / nbn) << 7, bn = (swz % nbn) << 7;
  const int wm = (wave >> 1) << 6, wn = (wave & 1) << 6;

  const int srow = lane >> 3;
  const int sslot = (lane & 7) ^ srow;
  const size_t rbytes = (size_t)K_ * 2;
  const char* aSrc = (const char*)Ap + (size_t)(bm + srow) * rbytes + (sslot << 4);
  const char* bSrc = (const char*)Bp + (size_t)(bn + srow) * rbytes + (sslot << 4);

  f32x4 acc[4][4];
  #pragma unroll
  for (int i = 0; i < 4; ++i)
    #pragma unroll
    for (int j = 0; j < 4; ++j) acc[i][j] = (f32x4){0.f, 0.f, 0.f, 0.f};

  const int fr = lane & 15, fs = lane >> 4;

  for (int ks = 0; ks < K_ / 64; ++ks) {
    const size_t ko = (size_t)ks << 7;   // 64 bf16 = 128 B per row per step
    #pragma unroll
    for (int i = 0; i < 4; ++i) {
      const int g = (wave << 2) + i;
      __builtin_amdgcn_global_load_lds(
          (const __attribute__((address_space(1))) void*)(aSrc + (size_t)(g << 3) * rbytes + ko),
          (__attribute__((address_space(3))) void*)((char*)As + (g << 10)), 16, 0, 0);
      __builtin_amdgcn_global_load_lds(
          (const __attribute__((address_space(1))) void*)(bSrc + (size_t)(g << 3) * rbytes + ko),
          (__attribute__((address_space(3))) void*)((char*)Bs + (g << 10)), 16, 0, 0);
    }
    __syncthreads();

    b16x8 a[4][2], b[4][2];
    #pragma unroll
    for (int t = 0; t < 4; ++t) {
      const int ar = wm + (t << 4) + fr;
      const char* pa = (const char*)As + (ar << 7);
      a[t][0] = *(const b16x8*)(pa + ((fs ^ (ar & 7)) << 4));
      a[t][1] = *(const b16x8*)(pa + (((4 + fs) ^ (ar & 7)) << 4));
      const int br = wn + (t << 4) + fr;
      const char* pb = (const char*)Bs + (br << 7);
      b[t][0] = *(const b16x8*)(pb + ((fs ^ (br & 7)) << 4));
      b[t][1] = *(const b16x8*)(pb + (((4 + fs) ^ (br & 7)) << 4));
    }
    #pragma unroll
    for (int mi = 0; mi < 4; ++mi)
      #pragma unroll
      for (int ni = 0; ni < 4; ++ni) {
        acc[mi][ni] = __builtin_amdgcn_mfma_f32_16x16x32_bf16(a[mi][0], b[ni][0], acc[mi][ni], 0, 0, 0);
        acc[mi][ni] = __builtin_amdgcn_mfma_f32_16x16x32_bf16(a[mi][1], b[ni][1], acc[mi][ni], 0, 0, 0);
      }
    __syncthreads();
  }

  const int g = lane >> 4;
  const int h = bn >> 7;
  if (wn == 0) {
    // zero-mean RMSNorm + RoPE -> bf16 nOut (B,H,N,D)
    float wv[4];
    #pragma unroll
    for (int ni = 0; ni < 4; ++ni) wv[ni] = nw[(ni << 4) + fr];
    #pragma unroll
    for (int mi = 0; mi < 4; ++mi) {
      #pragma unroll
      for (int r = 0; r < 4; ++r) {
        const int t = bm + wm + (mi << 4) + (g << 2) + r;
        float v0 = acc[mi][0][r], v1 = acc[mi][1][r];
        float v2 = acc[mi][2][r], v3 = acc[mi][3][r];
        float s = (v0 + v1) + (v2 + v3);
        #pragma unroll
        for (int off = 1; off < 16; off <<= 1) s += __shfl_xor(s, off);
        const float mean = s * (1.f / 64.f);
        v0 -= mean; v1 -= mean; v2 -= mean; v3 -= mean;
        float s2 = (v0*v0 + v1*v1) + (v2*v2 + v3*v3);
        #pragma unroll
        for (int off = 1; off < 16; off <<= 1) s2 += __shfl_xor(s2, off);
        const float rq = rsqrtf(s2 * (1.f / 64.f) + EPS_);
        const float x0 = v0 * rq * wv[0], x1 = v1 * rq * wv[1];
        const float x2 = v2 * rq * wv[2], x3 = v3 * rq * wv[3];
        const float* cr = cosb + (size_t)t * 64;
        const float* sr = sinb + (size_t)t * 64;
        const float o0 = x0 * cr[fr]    - x2 * sr[fr];
        const float o1 = x1 * cr[16+fr] - x3 * sr[16+fr];
        const float o2 = x2 * cr[32+fr] + x0 * sr[32+fr];
        const float o3 = x3 * cr[48+fr] + x1 * sr[48+fr];
        unsigned short* dp = nOut + (((size_t)((t >> 11) * H_ + h)) * N_ + (t & 2047)) * 64;
        dp[fr]      = f2bf(o0 * oscale);
        dp[16 + fr] = f2bf(o1 * oscale);
        dp[32 + fr] = f2bf(o2 * oscale);
        dp[48 + fr] = f2bf(o3 * oscale);
      }
    }
  } else if constexpr (MODE == 1) {
    // gate fp32 -> (B*N, C)
    float* gb = (float*)vOut;
    #pragma unroll
    for (int mi = 0; mi < 4; ++mi)
      #pragma unroll
      for (int r = 0; r < 4; ++r) {
        const int t = bm + wm + (mi << 4) + (g << 2) + r;
        float* gp = gb + (size_t)t * C_ + h * 64;
        #pragma unroll
        for (int ni = 0; ni < 4; ++ni) gp[(ni << 4) + fr] = acc[mi][ni][r];
      }
  } else {
    // V -> bf16 transposed (B,H,D,N)
    unsigned short* vt = (unsigned short*)vOut;
    #pragma unroll
    for (int mi = 0; mi < 4; ++mi) {
      const int t0 = bm + wm + (mi << 4) + (g << 2);
      const int bb = t0 >> 11, n0 = t0 & 2047;
      #pragma unroll
      for (int ni = 0; ni < 4; ++ni) {
        const int dv = (ni << 4) + fr;
        ushort4 pk = make_ushort4(f2bf(acc[mi][ni][0]), f2bf(acc[mi][ni][1]),
                                  f2bf(acc[mi][ni][2]), f2bf(acc[mi][ni][3]));
        *(ushort4*)(vt + ((size_t)(bb * H_ + h) * 64 + dv) * N_ + n0) = pk;
      }
    }
  }
}

// ---------- split-bf16 (hi/lo, 3-MFMA) GEMM NT for the output projection ----------
__global__ __launch_bounds__(256) void gemm_nt_hilo(
    const unsigned short* __restrict__ Ap, const unsigned short* __restrict__ Bp,
    float* __restrict__ Cm, int M, int N, const float* __restrict__ bias)
{
  __shared__ __align__(16) unsigned short As[128 * 64];
  __shared__ __align__(16) unsigned short Bs[128 * 64];
  const int tid = threadIdx.x, lane = tid & 63, wave = tid >> 6;

  const int nwg = gridDim.x, id = blockIdx.x;
  const int swz = (id & 7) * (nwg >> 3) + (id >> 3);
  const int nbn = N >> 7;
  const int bm = (swz / nbn) << 7, bn = (swz % nbn) << 7;
  const int wm = (wave >> 1) << 6, wn = (wave & 1) << 6;

  const int srow = lane >> 3;
  const int sslot = (lane & 7) ^ srow;
  const size_t rbytes = (size_t)K_ * 4;
  const char* aSrc = (const char*)Ap + (size_t)(bm + srow) * rbytes + (sslot << 4);
  const char* bSrc = (const char*)Bp + (size_t)(bn + srow) * rbytes + (sslot << 4);

  f32x4 acc[4][4];
  #pragma unroll
  for (int i = 0; i < 4; ++i)
    #pragma unroll
    for (int j = 0; j < 4; ++j) acc[i][j] = (f32x4){0.f, 0.f, 0.f, 0.f};

  const int fr = lane & 15, fs = lane >> 4;
  const int hoff = (fs ^ (fr & 7)) << 4;

  for (int ks = 0; ks < K_ / 32; ++ks) {
    const size_t ko = (size_t)ks << 7;
    #pragma unroll
    for (int i = 0; i < 4; ++i) {
      const int g = (wave << 2) + i;
      __builtin_amdgcn_global_load_lds(
          (const __attribute__((address_space(1))) void*)(aSrc + (size_t)(g << 3) * rbytes + ko),
          (__attribute__((address_space(3))) void*)((char*)As + (g << 10)), 16, 0, 0);
      __builtin_amdgcn_global_load_lds(
          (const __attribute__((address_space(1))) void*)(bSrc + (size_t)(g << 3) * rbytes + ko),
          (__attribute__((address_space(3))) void*)((char*)Bs + (g << 10)), 16, 0, 0);
    }
    __syncthreads();

    b16x8 ah[4], al[4], bh[4], bl[4];
    #pragma unroll
    for (int t = 0; t < 4; ++t) {
      const char* pa = (const char*)As + ((wm + (t << 4) + fr) << 7);
      ah[t] = *(const b16x8*)(pa + hoff);
      al[t] = *(const b16x8*)(pa + (hoff ^ 64));
      const char* pb = (const char*)Bs + ((wn + (t << 4) + fr) << 7);
      bh[t] = *(const b16x8*)(pb + hoff);
      bl[t] = *(const b16x8*)(pb + (hoff ^ 64));
    }
    #pragma unroll
    for (int mi = 0; mi < 4; ++mi)
      #pragma unroll
      for (int ni = 0; ni < 4; ++ni) {
        acc[mi][ni] = __builtin_amdgcn_mfma_f32_16x16x32_bf16(ah[mi], bh[ni], acc[mi][ni], 0, 0, 0);
        acc[mi][ni] = __builtin_amdgcn_mfma_f32_16x16x32_bf16(al[mi], bh[ni], acc[mi][ni], 0, 0, 0);
        acc[mi][ni] = __builtin_amdgcn_mfma_f32_16x16x32_bf16(ah[mi], bl[ni], acc[mi][ni], 0, 0, 0);
      }
    __syncthreads();
  }

  const int rbase = (lane >> 4) << 2;
  #pragma unroll
  for (int mi = 0; mi < 4; ++mi)
    #pragma unroll
    for (int ni = 0; ni < 4; ++ni) {
      const int n = bn + wn + (ni << 4) + fr;
      const float badd = bias ? bias[n] : 0.f;
      #pragma unroll
      for (int r = 0; r < 4; ++r) {
        const int m = bm + wm + (mi << 4) + rbase + r;
        Cm[(size_t)m * N + n] = acc[mi][ni][r] + badd;
      }
    }
}

// ---------- flash attention: swapped QK^T, STATIC-max softmax ----------
__global__ __launch_bounds__(256) void flash_bf16(
    const unsigned short* __restrict__ Qb, const unsigned short* __restrict__ Kb,
    const unsigned short* __restrict__ Vt, const float* __restrict__ gateb,
    unsigned short* __restrict__ gp)
{
  const int b = blockIdx.z, h = blockIdx.y, q0 = blockIdx.x * 64;
  const int tid = threadIdx.x, lane = tid & 63, wave = tid >> 6;
  __shared__ __align__(16) unsigned short Ks[128 * 64];   // 128 kv-rows x 128B (swz)
  __shared__ __align__(16) unsigned short Vss[64 * 128];  // 64 d-rows x 256B (swz)
  __shared__ __align__(16) __bf16 Ps[4][16][136];         // per-wave P[q][kv]
  const int bh = b * H_ + h;
  const int g = lane >> 4, fr = lane & 15;

  b16x8 qf0, qf1;
  {
    const unsigned short* Qrow = Qb + ((size_t)bh * N_ + q0 + wave*16 + fr) * D_;
    qf0 = *(const b16x8*)(Qrow + (g << 3));
    qf1 = *(const b16x8*)(Qrow + 32 + (g << 3));
  }

  f32x4 acc[4];
  #pragma unroll
  for (int r = 0; r < 4; ++r) acc[r] = (f32x4){0.f, 0.f, 0.f, 0.f};
  float lreg = 0.f;   // lane-local partial denominator (q = fr)

  const unsigned short* Kbh  = Kb + (size_t)bh * N_ * D_;
  const unsigned short* Vtbh = Vt + (size_t)bh * D_ * N_;
  const int swzK = ((lane & 7) ^ (lane >> 3)) << 4;
  __bf16* Pw = &Ps[wave][0][0] + fr * 136;

  for (int j0 = 0; j0 < N_; j0 += 128) {
    #pragma unroll
    for (int i = 0; i < 4; ++i) {
      const int gg = wave * 4 + i;
      const char* ksrc = (const char*)(Kbh + (size_t)(j0 + gg * 8) * D_) + (lane >> 3) * 128 + swzK;
      __builtin_amdgcn_global_load_lds(
          (const __attribute__((address_space(1))) void*)ksrc,
          (__attribute__((address_space(3))) void*)((char*)Ks + gg * 1024), 16, 0, 0);
      const int dv = gg * 4 + g;
      const char* vsrc = (const char*)(Vtbh + (size_t)dv * N_ + j0) + ((fr ^ (dv & 7)) << 4);
      __builtin_amdgcn_global_load_lds(
          (const __attribute__((address_space(1))) void*)vsrc,
          (__attribute__((address_space(3))) void*)((char*)Vss + gg * 1024), 16, 0, 0);
    }
    __syncthreads();

    // QK^T swapped: lane holds q=fr, kv = t*16 + g*4 + r (log2 units)
    f32x4 sacc[8];
    const int cb0 = g << 4;
    #pragma unroll
    for (int t = 0; t < 8; ++t) {
      sacc[t] = (f32x4){0.f, 0.f, 0.f, 0.f};
      const int krow = t * 16 + fr;
      const char* kb = (const char*)Ks + krow * 128;
      const int f = (krow & 7) << 4;
      b16x8 kf0 = *(const b16x8*)(kb + (cb0 ^ f));
      b16x8 kf1 = *(const b16x8*)(kb + ((64 + cb0) ^ f));
      sacc[t] = __builtin_amdgcn_mfma_f32_16x16x32_bf16(kf0, qf0, sacc[t], 0, 0, 0);
      sacc[t] = __builtin_amdgcn_mfma_f32_16x16x32_bf16(kf1, qf1, sacc[t], 0, 0, 0);
    }

    // P = exp2(S - SMAX_): |S| <= 11.54 (Cauchy-Schwarz, zmRMS norm) -> no
    // running max, no rescale; softmax is shift-invariant, bf16 scale-invariant.
    #pragma unroll
    for (int t = 0; t < 8; ++t) {
      union { __bf16 hb[4]; ushort4 u4; } pk;
      #pragma unroll
      for (int r = 0; r < 4; ++r) {
        const float p = __builtin_amdgcn_exp2f(sacc[t][r] - SMAX_);
        lreg += p;
        pk.hb[r] = (__bf16)p;
      }
      *(ushort4*)(Pw + t * 16 + (g << 2)) = pk.u4;
    }

    // PV: O[16q x 64d] += P @ V
    b16x8 pf[4];
    #pragma unroll
    for (int c = 0; c < 4; ++c)
      pf[c] = *(const b16x8*)(Pw + c * 32 + (g << 3));
    #pragma unroll
    for (int dt = 0; dt < 4; ++dt) {
      const int vrow = dt * 16 + fr;
      const char* vb = (const char*)Vss + vrow * 256;
      const int fv = (vrow & 7) << 4;
      #pragma unroll
      for (int c = 0; c < 4; ++c) {
        b16x8 vf = *(const b16x8*)(vb + ((c * 64 + cb0) ^ fv));
        acc[dt] = __builtin_amdgcn_mfma_f32_16x16x32_bf16(pf[c], vf, acc[dt], 0, 0, 0);
      }
    }
    __syncthreads();
  }

  // finalize denominator: reduce the 4 lane-groups holding q=fr
  lreg += __shfl_xor(lreg, 16);
  lreg += __shfl_xor(lreg, 32);

  // epilogue: normalize, sigmoid gate, write hi/lo-packed gp (B*N, 2048)
  #pragma unroll
  for (int r = 0; r < 4; ++r) {
    const float lr = __shfl(lreg, (g << 2) + r);
    const float inv = 1.f / lr;
    const int q = q0 + wave * 16 + (g << 2) + r;
    const size_t rowbase = (size_t)(b * N_ + q) * PK_;
    #pragma unroll
    for (int dt = 0; dt < 4; ++dt) {
      const int d = (dt << 4) + fr;
      const float o = acc[dt][r] * inv;
      const float gate = gateb[(size_t)(b * N_ + q) * C_ + h * 64 + d];
      const float sg = 1.f / (1.f + __expf(-gate));
      const float val = o * sg;
      const int k = h * 64 + d;
      unsigned short* p = gp + rowbase + ((k >> 5) << 6) + (k & 31);
      const unsigned short hi = f2bf(val);
      p[0]  = hi;
      p[32] = f2bf(val - bf2f(hi));
    }
  }
}

extern "C" void kernel_launch(void* const* d_in, const int* in_sizes, int n_in,
                              void* d_out, int out_size, void* d_ws, size_t ws_size,
                              hipStream_t stream) {
  const float* x    = (const float*)d_in[0];
  const float* ctx  = (const float*)d_in[1];
  const float* cosb = (const float*)d_in[2];
  const float* sinb = (const float*)d_in[3];
  const float* Wq   = (const float*)d_in[4];
  const float* Wkv  = (const float*)d_in[5];
  const float* Wo   = (const float*)d_in[6];
  const float* bo   = (const float*)d_in[7];
  const float* qnw  = (const float*)d_in[8];
  const float* knw  = (const float*)d_in[9];
  float* out = (float*)d_out;

  char* ws = (char*)d_ws;
  unsigned short* Qb   = (unsigned short*)(ws);                    // 8M  @0
  unsigned short* Kb   = (unsigned short*)(ws + (size_t)8388608);  // 8M  @8M
  unsigned short* Vt   = (unsigned short*)(ws + (size_t)16777216); // 8M  @16M
  float*          gate = (float*)(ws + (size_t)25165824);          // 16M @24M
  unsigned short* gpk  = (unsigned short*)(ws + (size_t)41943040); // 16M @40M
  unsigned short* xb   = (unsigned short*)(ws + (size_t)58720256); // 8M  @56M
  unsigned short* cb   = (unsigned short*)(ws + (size_t)67108864); // 8M  @64M
  unsigned short* wqb  = (unsigned short*)(ws + (size_t)75497472); // 4M  @72M
  unsigned short* wkvb = (unsigned short*)(ws + (size_t)79691776); // 4M  @76M
  unsigned short* wop  = (unsigned short*)(ws + (size_t)83886080); // 4M  @80M

  const dim3 blk(256);
  pack_all<<<dim3(13312), blk, 0, stream>>>(x, Wq, ctx, Wkv, Wo, xb, wqb, cb, wkvb, wop);
  gemm_nt_bf16<1><<<dim3(512), blk, 0, stream>>>(xb, wqb, 4096, 2048,
                                                 cosb, sinb, qnw, Qb, gate, 0.125f * LOG2E_);
  gemm_nt_bf16<2><<<dim3(512), blk, 0, stream>>>(cb, wkvb, 4096, 2048,
                                                 cosb, sinb, knw, Kb, Vt, 1.0f);
  flash_bf16<<<dim3(32, 16, 2), blk, 0, stream>>>(Qb, Kb, Vt, gate, gpk);
  gemm_nt_hilo<<<dim3(256), blk, 0, stream>>>(gpk, wop, out, 4096, 1024, bo);
}

// Round 8
// 170.368 us; speedup vs baseline: 7.4407x; 1.0850x over previous
//
#include <hip/hip_runtime.h>
#include <cstdint>
#include <cstddef>

// CrossAttention r8: r6 pipeline (passing, 185us) with flash restructured for
// 2x arithmetic intensity at the SAME verified 16x16 fragment layouts:
// each wave owns 32 q-rows (two 16-row sets), K/V LDS fragments read once and
// shared across both sets, P streamed per-t (low VGPR), setprio around MFMA.
// r7's 32x32 in-register-P path is abandoned (unverified layout stack failed).
// Launches: pack_all | gemm_bf16<1> | gemm_bf16<2> | flash | gemm_hilo  (5)
// ws (84MiB): Qb 8M@0 | Kb 8M@8M | Vt 8M@16M | gate 16M@24M | gpk 16M@40M
//             | xb 8M@56M | cb 8M@64M | wqb 4M@72M | wkvb 4M@76M | wop 4M@80M

#define B_ 2
#define N_ 2048
#define C_ 1024
#define H_ 16
#define D_ 64
#define K_ 1024
#define PK_ 2048
#define EPS_ 1e-6f
#define LOG2E_ 1.44269504088896f
#define SMAX_ 12.0f

typedef __bf16 b16x8 __attribute__((ext_vector_type(8)));
typedef float f32x4 __attribute__((ext_vector_type(4)));

__device__ __forceinline__ unsigned short f2bf(float f) {
  union { float f; unsigned u; } a; a.f = f;
  unsigned r = a.u + 0x7FFFu + ((a.u >> 16) & 1u);
  return (unsigned short)(r >> 16);
}
__device__ __forceinline__ float bf2f(unsigned short u) {
  union { unsigned u; float f; } a; a.u = ((unsigned)u) << 16; return a.f;
}

__device__ __forceinline__ void cast_one(const float* __restrict__ src,
                                         unsigned short* __restrict__ dst, int e) {
  float4 v = *(const float4*)(src + e);
  *(ushort4*)(dst + e) = make_ushort4(f2bf(v.x), f2bf(v.y), f2bf(v.z), f2bf(v.w));
}

__device__ __forceinline__ void pack_one(const float* __restrict__ src,
                                         unsigned short* __restrict__ dst, int e) {
  float4 v = *(const float4*)(src + e);
  const int r = e >> 10, k = e & 1023;
  unsigned short* p = dst + ((size_t)r << 11) + ((k >> 5) << 6) + (k & 31);
  const unsigned short h0 = f2bf(v.x), h1 = f2bf(v.y), h2 = f2bf(v.z), h3 = f2bf(v.w);
  *(ushort4*)p = make_ushort4(h0, h1, h2, h3);
  *(ushort4*)(p + 32) = make_ushort4(f2bf(v.x - bf2f(h0)), f2bf(v.y - bf2f(h1)),
                                     f2bf(v.z - bf2f(h2)), f2bf(v.w - bf2f(h3)));
}

__global__ __launch_bounds__(256) void pack_all(
    const float* __restrict__ x, const float* __restrict__ Wq,
    const float* __restrict__ ctx, const float* __restrict__ Wkv,
    const float* __restrict__ Wo,
    unsigned short* __restrict__ xb, unsigned short* __restrict__ wqb,
    unsigned short* __restrict__ cb, unsigned short* __restrict__ wkvb,
    unsigned short* __restrict__ wop)
{
  const int e = (blockIdx.x * 256 + threadIdx.x) << 2;
  if (e < 4194304)       cast_one(x,   xb,  e);
  else if (e < 6291456)  cast_one(Wq,  wqb, e - 4194304);
  else if (e < 10485760) cast_one(ctx, cb,  e - 6291456);
  else if (e < 12582912) cast_one(Wkv, wkvb, e - 10485760);
  else                   pack_one(Wo,  wop, e - 12582912);
}

// ---------- single-bf16 GEMM NT with fused epilogues (unchanged from r6) ----------
template<int MODE>
__global__ __launch_bounds__(256) void gemm_nt_bf16(
    const unsigned short* __restrict__ Ap, const unsigned short* __restrict__ Bp,
    int M, int N,
    const float* __restrict__ cosb, const float* __restrict__ sinb,
    const float* __restrict__ nw, unsigned short* __restrict__ nOut,
    void* __restrict__ vOut, float oscale)
{
  __shared__ __align__(16) unsigned short As[128 * 64];
  __shared__ __align__(16) unsigned short Bs[128 * 64];
  const int tid = threadIdx.x, lane = tid & 63, wave = tid >> 6;

  const int nwg = gridDim.x, id = blockIdx.x;
  const int swz = (id & 7) * (nwg >> 3) + (id >> 3);
  const int nbn = N >> 7;
  const int bm = (swz / nbn) << 7, bn = (swz % nbn) << 7;
  const int wm = (wave >> 1) << 6, wn = (wave & 1) << 6;

  const int srow = lane >> 3;
  const int sslot = (lane & 7) ^ srow;
  const size_t rbytes = (size_t)K_ * 2;
  const char* aSrc = (const char*)Ap + (size_t)(bm + srow) * rbytes + (sslot << 4);
  const char* bSrc = (const char*)Bp + (size_t)(bn + srow) * rbytes + (sslot << 4);

  f32x4 acc[4][4];
  #pragma unroll
  for (int i = 0; i < 4; ++i)
    #pragma unroll
    for (int j = 0; j < 4; ++j) acc[i][j] = (f32x4){0.f, 0.f, 0.f, 0.f};

  const int fr = lane & 15, fs = lane >> 4;

  for (int ks = 0; ks < K_ / 64; ++ks) {
    const size_t ko = (size_t)ks << 7;
    #pragma unroll
    for (int i = 0; i < 4; ++i) {
      const int g = (wave << 2) + i;
      __builtin_amdgcn_global_load_lds(
          (const __attribute__((address_space(1))) void*)(aSrc + (size_t)(g << 3) * rbytes + ko),
          (__attribute__((address_space(3))) void*)((char*)As + (g << 10)), 16, 0, 0);
      __builtin_amdgcn_global_load_lds(
          (const __attribute__((address_space(1))) void*)(bSrc + (size_t)(g << 3) * rbytes + ko),
          (__attribute__((address_space(3))) void*)((char*)Bs + (g << 10)), 16, 0, 0);
    }
    __syncthreads();

    b16x8 a[4][2], b[4][2];
    #pragma unroll
    for (int t = 0; t < 4; ++t) {
      const int ar = wm + (t << 4) + fr;
      const char* pa = (const char*)As + (ar << 7);
      a[t][0] = *(const b16x8*)(pa + ((fs ^ (ar & 7)) << 4));
      a[t][1] = *(const b16x8*)(pa + (((4 + fs) ^ (ar & 7)) << 4));
      const int br = wn + (t << 4) + fr;
      const char* pb = (const char*)Bs + (br << 7);
      b[t][0] = *(const b16x8*)(pb + ((fs ^ (br & 7)) << 4));
      b[t][1] = *(const b16x8*)(pb + (((4 + fs) ^ (br & 7)) << 4));
    }
    #pragma unroll
    for (int mi = 0; mi < 4; ++mi)
      #pragma unroll
      for (int ni = 0; ni < 4; ++ni) {
        acc[mi][ni] = __builtin_amdgcn_mfma_f32_16x16x32_bf16(a[mi][0], b[ni][0], acc[mi][ni], 0, 0, 0);
        acc[mi][ni] = __builtin_amdgcn_mfma_f32_16x16x32_bf16(a[mi][1], b[ni][1], acc[mi][ni], 0, 0, 0);
      }
    __syncthreads();
  }

  const int g = lane >> 4;
  const int h = bn >> 7;
  if (wn == 0) {
    float wv[4];
    #pragma unroll
    for (int ni = 0; ni < 4; ++ni) wv[ni] = nw[(ni << 4) + fr];
    #pragma unroll
    for (int mi = 0; mi < 4; ++mi) {
      #pragma unroll
      for (int r = 0; r < 4; ++r) {
        const int t = bm + wm + (mi << 4) + (g << 2) + r;
        float v0 = acc[mi][0][r], v1 = acc[mi][1][r];
        float v2 = acc[mi][2][r], v3 = acc[mi][3][r];
        float s = (v0 + v1) + (v2 + v3);
        #pragma unroll
        for (int off = 1; off < 16; off <<= 1) s += __shfl_xor(s, off);
        const float mean = s * (1.f / 64.f);
        v0 -= mean; v1 -= mean; v2 -= mean; v3 -= mean;
        float s2 = (v0*v0 + v1*v1) + (v2*v2 + v3*v3);
        #pragma unroll
        for (int off = 1; off < 16; off <<= 1) s2 += __shfl_xor(s2, off);
        const float rq = rsqrtf(s2 * (1.f / 64.f) + EPS_);
        const float x0 = v0 * rq * wv[0], x1 = v1 * rq * wv[1];
        const float x2 = v2 * rq * wv[2], x3 = v3 * rq * wv[3];
        const float* cr = cosb + (size_t)t * 64;
        const float* sr = sinb + (size_t)t * 64;
        const float o0 = x0 * cr[fr]    - x2 * sr[fr];
        const float o1 = x1 * cr[16+fr] - x3 * sr[16+fr];
        const float o2 = x2 * cr[32+fr] + x0 * sr[32+fr];
        const float o3 = x3 * cr[48+fr] + x1 * sr[48+fr];
        unsigned short* dp = nOut + (((size_t)((t >> 11) * H_ + h)) * N_ + (t & 2047)) * 64;
        dp[fr]      = f2bf(o0 * oscale);
        dp[16 + fr] = f2bf(o1 * oscale);
        dp[32 + fr] = f2bf(o2 * oscale);
        dp[48 + fr] = f2bf(o3 * oscale);
      }
    }
  } else if constexpr (MODE == 1) {
    float* gb = (float*)vOut;
    #pragma unroll
    for (int mi = 0; mi < 4; ++mi)
      #pragma unroll
      for (int r = 0; r < 4; ++r) {
        const int t = bm + wm + (mi << 4) + (g << 2) + r;
        float* gp = gb + (size_t)t * C_ + h * 64;
        #pragma unroll
        for (int ni = 0; ni < 4; ++ni) gp[(ni << 4) + fr] = acc[mi][ni][r];
      }
  } else {
    unsigned short* vt = (unsigned short*)vOut;
    #pragma unroll
    for (int mi = 0; mi < 4; ++mi) {
      const int t0 = bm + wm + (mi << 4) + (g << 2);
      const int bb = t0 >> 11, n0 = t0 & 2047;
      #pragma unroll
      for (int ni = 0; ni < 4; ++ni) {
        const int dv = (ni << 4) + fr;
        ushort4 pk = make_ushort4(f2bf(acc[mi][ni][0]), f2bf(acc[mi][ni][1]),
                                  f2bf(acc[mi][ni][2]), f2bf(acc[mi][ni][3]));
        *(ushort4*)(vt + ((size_t)(bb * H_ + h) * 64 + dv) * N_ + n0) = pk;
      }
    }
  }
}

// ---------- split-bf16 (hi/lo, 3-MFMA) GEMM NT for the output projection ----------
__global__ __launch_bounds__(256) void gemm_nt_hilo(
    const unsigned short* __restrict__ Ap, const unsigned short* __restrict__ Bp,
    float* __restrict__ Cm, int M, int N, const float* __restrict__ bias)
{
  __shared__ __align__(16) unsigned short As[128 * 64];
  __shared__ __align__(16) unsigned short Bs[128 * 64];
  const int tid = threadIdx.x, lane = tid & 63, wave = tid >> 6;

  const int nwg = gridDim.x, id = blockIdx.x;
  const int swz = (id & 7) * (nwg >> 3) + (id >> 3);
  const int nbn = N >> 7;
  const int bm = (swz / nbn) << 7, bn = (swz % nbn) << 7;
  const int wm = (wave >> 1) << 6, wn = (wave & 1) << 6;

  const int srow = lane >> 3;
  const int sslot = (lane & 7) ^ srow;
  const size_t rbytes = (size_t)K_ * 4;
  const char* aSrc = (const char*)Ap + (size_t)(bm + srow) * rbytes + (sslot << 4);
  const char* bSrc = (const char*)Bp + (size_t)(bn + srow) * rbytes + (sslot << 4);

  f32x4 acc[4][4];
  #pragma unroll
  for (int i = 0; i < 4; ++i)
    #pragma unroll
    for (int j = 0; j < 4; ++j) acc[i][j] = (f32x4){0.f, 0.f, 0.f, 0.f};

  const int fr = lane & 15, fs = lane >> 4;
  const int hoff = (fs ^ (fr & 7)) << 4;

  for (int ks = 0; ks < K_ / 32; ++ks) {
    const size_t ko = (size_t)ks << 7;
    #pragma unroll
    for (int i = 0; i < 4; ++i) {
      const int g = (wave << 2) + i;
      __builtin_amdgcn_global_load_lds(
          (const __attribute__((address_space(1))) void*)(aSrc + (size_t)(g << 3) * rbytes + ko),
          (__attribute__((address_space(3))) void*)((char*)As + (g << 10)), 16, 0, 0);
      __builtin_amdgcn_global_load_lds(
          (const __attribute__((address_space(1))) void*)(bSrc + (size_t)(g << 3) * rbytes + ko),
          (__attribute__((address_space(3))) void*)((char*)Bs + (g << 10)), 16, 0, 0);
    }
    __syncthreads();

    b16x8 ah[4], al[4], bh[4], bl[4];
    #pragma unroll
    for (int t = 0; t < 4; ++t) {
      const char* pa = (const char*)As + ((wm + (t << 4) + fr) << 7);
      ah[t] = *(const b16x8*)(pa + hoff);
      al[t] = *(const b16x8*)(pa + (hoff ^ 64));
      const char* pb = (const char*)Bs + ((wn + (t << 4) + fr) << 7);
      bh[t] = *(const b16x8*)(pb + hoff);
      bl[t] = *(const b16x8*)(pb + (hoff ^ 64));
    }
    #pragma unroll
    for (int mi = 0; mi < 4; ++mi)
      #pragma unroll
      for (int ni = 0; ni < 4; ++ni) {
        acc[mi][ni] = __builtin_amdgcn_mfma_f32_16x16x32_bf16(ah[mi], bh[ni], acc[mi][ni], 0, 0, 0);
        acc[mi][ni] = __builtin_amdgcn_mfma_f32_16x16x32_bf16(al[mi], bh[ni], acc[mi][ni], 0, 0, 0);
        acc[mi][ni] = __builtin_amdgcn_mfma_f32_16x16x32_bf16(ah[mi], bl[ni], acc[mi][ni], 0, 0, 0);
      }
    __syncthreads();
  }

  const int rbase = (lane >> 4) << 2;
  #pragma unroll
  for (int mi = 0; mi < 4; ++mi)
    #pragma unroll
    for (int ni = 0; ni < 4; ++ni) {
      const int n = bn + wn + (ni << 4) + fr;
      const float badd = bias ? bias[n] : 0.f;
      #pragma unroll
      for (int r = 0; r < 4; ++r) {
        const int m = bm + wm + (mi << 4) + rbase + r;
        Cm[(size_t)m * N + n] = acc[mi][ni][r] + badd;
      }
    }
}

// ---------- flash attention: 32 q-rows/wave (2 sets), shared K/V frags ----------
// Same verified 16x16 layouts/swizzles/numerics as r6; QBLK=128/block.
__global__ __launch_bounds__(256) void flash_bf16(
    const unsigned short* __restrict__ Qb, const unsigned short* __restrict__ Kb,
    const unsigned short* __restrict__ Vt, const float* __restrict__ gateb,
    unsigned short* __restrict__ gp)
{
  const int b = blockIdx.z, h = blockIdx.y, q0 = blockIdx.x * 128;
  const int tid = threadIdx.x, lane = tid & 63, wave = tid >> 6;
  __shared__ __align__(16) unsigned short Ks[128 * 64];     // 128 kv x 128B (swz)
  __shared__ __align__(16) unsigned short Vss[64 * 128];    // 64 d x 256B (swz)
  __shared__ __align__(16) __bf16 Ps[4][2][16][136];        // per-wave, 2 q-sets
  const int bh = b * H_ + h;
  const int g = lane >> 4, fr = lane & 15;

  // two q-sets per wave: rows q0 + wave*32 + {0,16} + fr
  b16x8 qA0, qA1, qB0, qB1;
  {
    const unsigned short* QrowA = Qb + ((size_t)bh * N_ + q0 + wave*32 + fr) * D_;
    qA0 = *(const b16x8*)(QrowA + (g << 3));
    qA1 = *(const b16x8*)(QrowA + 32 + (g << 3));
    qB0 = *(const b16x8*)(QrowA + 16 * D_ + (g << 3));
    qB1 = *(const b16x8*)(QrowA + 16 * D_ + 32 + (g << 3));
  }

  f32x4 oA[4], oB[4];
  #pragma unroll
  for (int r = 0; r < 4; ++r) {
    oA[r] = (f32x4){0.f, 0.f, 0.f, 0.f};
    oB[r] = (f32x4){0.f, 0.f, 0.f, 0.f};
  }
  float lA = 0.f, lB = 0.f;   // lane-local partial denominators (q = fr)

  const unsigned short* Kbh  = Kb + (size_t)bh * N_ * D_;
  const unsigned short* Vtbh = Vt + (size_t)bh * D_ * N_;
  const int swzK = ((lane & 7) ^ (lane >> 3)) << 4;
  __bf16* PwA = &Ps[wave][0][0][0] + fr * 136;
  __bf16* PwB = &Ps[wave][1][0][0] + fr * 136;

  for (int j0 = 0; j0 < N_; j0 += 128) {
    // stage K (128x128B) + V^T (64x256B), pre-swizzled source, linear dest
    #pragma unroll
    for (int i = 0; i < 4; ++i) {
      const int gg = wave * 4 + i;
      const char* ksrc = (const char*)(Kbh + (size_t)(j0 + gg * 8) * D_) + (lane >> 3) * 128 + swzK;
      __builtin_amdgcn_global_load_lds(
          (const __attribute__((address_space(1))) void*)ksrc,
          (__attribute__((address_space(3))) void*)((char*)Ks + gg * 1024), 16, 0, 0);
      const int dv = gg * 4 + (lane >> 4);
      const char* vsrc = (const char*)(Vtbh + (size_t)dv * N_ + j0) + (((lane & 15) ^ (dv & 7)) << 4);
      __builtin_amdgcn_global_load_lds(
          (const __attribute__((address_space(1))) void*)vsrc,
          (__attribute__((address_space(3))) void*)((char*)Vss + gg * 1024), 16, 0, 0);
    }
    __syncthreads();

    const int cb0 = g << 4;
    // QK^T + streamed softmax: each K fragment read ONCE, feeds both q-sets.
    __builtin_amdgcn_s_setprio(1);
    #pragma unroll
    for (int t = 0; t < 8; ++t) {
      const int krow = t * 16 + fr;
      const char* kbp = (const char*)Ks + krow * 128;
      const int f = (krow & 7) << 4;
      b16x8 kf0 = *(const b16x8*)(kbp + (cb0 ^ f));
      b16x8 kf1 = *(const b16x8*)(kbp + ((64 + cb0) ^ f));
      f32x4 sA = __builtin_amdgcn_mfma_f32_16x16x32_bf16(kf0, qA0, (f32x4){0.f,0.f,0.f,0.f}, 0, 0, 0);
      sA = __builtin_amdgcn_mfma_f32_16x16x32_bf16(kf1, qA1, sA, 0, 0, 0);
      f32x4 sB = __builtin_amdgcn_mfma_f32_16x16x32_bf16(kf0, qB0, (f32x4){0.f,0.f,0.f,0.f}, 0, 0, 0);
      sB = __builtin_amdgcn_mfma_f32_16x16x32_bf16(kf1, qB1, sB, 0, 0, 0);
      union { __bf16 hb[4]; ushort4 u4; } pkA, pkB;
      #pragma unroll
      for (int r = 0; r < 4; ++r) {
        const float pA = __builtin_amdgcn_exp2f(sA[r] - SMAX_);
        lA += pA;
        pkA.hb[r] = (__bf16)pA;
        const float pB = __builtin_amdgcn_exp2f(sB[r] - SMAX_);
        lB += pB;
        pkB.hb[r] = (__bf16)pB;
      }
      *(ushort4*)(PwA + t * 16 + (g << 2)) = pkA.u4;
      *(ushort4*)(PwB + t * 16 + (g << 2)) = pkB.u4;
    }
    __builtin_amdgcn_s_setprio(0);

    b16x8 pfA[4], pfB[4];
    #pragma unroll
    for (int c = 0; c < 4; ++c) {
      pfA[c] = *(const b16x8*)(PwA + c * 32 + (g << 3));
      pfB[c] = *(const b16x8*)(PwB + c * 32 + (g << 3));
    }

    // PV: each V fragment read ONCE, feeds both q-sets.
    __builtin_amdgcn_s_setprio(1);
    #pragma unroll
    for (int dt = 0; dt < 4; ++dt) {
      const int vrow = dt * 16 + fr;
      const char* vbp = (const char*)Vss + vrow * 256;
      const int fv = (vrow & 7) << 4;
      #pragma unroll
      for (int c = 0; c < 4; ++c) {
        b16x8 vf = *(const b16x8*)(vbp + ((c * 64 + cb0) ^ fv));
        oA[dt] = __builtin_amdgcn_mfma_f32_16x16x32_bf16(pfA[c], vf, oA[dt], 0, 0, 0);
        oB[dt] = __builtin_amdgcn_mfma_f32_16x16x32_bf16(pfB[c], vf, oB[dt], 0, 0, 0);
      }
    }
    __builtin_amdgcn_s_setprio(0);
    __syncthreads();
  }

  // finalize denominators (4 lane-groups hold disjoint kv for same q=fr)
  lA += __shfl_xor(lA, 16); lA += __shfl_xor(lA, 32);
  lB += __shfl_xor(lB, 16); lB += __shfl_xor(lB, 32);

  // epilogue: normalize, sigmoid gate, hi/lo-packed gp (B*N, 2048), both sets
  #pragma unroll
  for (int r = 0; r < 4; ++r) {
    const float lqA = __shfl(lA, (g << 2) + r);
    const float lqB = __shfl(lB, (g << 2) + r);
    #pragma unroll
    for (int set = 0; set < 2; ++set) {
      const float inv = 1.f / (set ? lqB : lqA);
      const int q = q0 + wave * 32 + set * 16 + (g << 2) + r;
      const size_t qa = (size_t)(b * N_ + q);
      #pragma unroll
      for (int dt = 0; dt < 4; ++dt) {
        const int d = (dt << 4) + fr;
        const float o = (set ? oB[dt][r] : oA[dt][r]) * inv;
        const float gate = gateb[qa * C_ + h * 64 + d];
        const float sg = 1.f / (1.f + __expf(-gate));
        const float val = o * sg;
        const int k = h * 64 + d;
        unsigned short* p = gp + qa * PK_ + ((k >> 5) << 6) + (k & 31);
        const unsigned short hi = f2bf(val);
        p[0]  = hi;
        p[32] = f2bf(val - bf2f(hi));
      }
    }
  }
}

extern "C" void kernel_launch(void* const* d_in, const int* in_sizes, int n_in,
                              void* d_out, int out_size, void* d_ws, size_t ws_size,
                              hipStream_t stream) {
  const float* x    = (const float*)d_in[0];
  const float* ctx  = (const float*)d_in[1];
  const float* cosb = (const float*)d_in[2];
  const float* sinb = (const float*)d_in[3];
  const float* Wq   = (const float*)d_in[4];
  const float* Wkv  = (const float*)d_in[5];
  const float* Wo   = (const float*)d_in[6];
  const float* bo   = (const float*)d_in[7];
  const float* qnw  = (const float*)d_in[8];
  const float* knw  = (const float*)d_in[9];
  float* out = (float*)d_out;

  char* ws = (char*)d_ws;
  unsigned short* Qb   = (unsigned short*)(ws);                    // 8M  @0
  unsigned short* Kb   = (unsigned short*)(ws + (size_t)8388608);  // 8M  @8M
  unsigned short* Vt   = (unsigned short*)(ws + (size_t)16777216); // 8M  @16M
  float*          gate = (float*)(ws + (size_t)25165824);          // 16M @24M
  unsigned short* gpk  = (unsigned short*)(ws + (size_t)41943040); // 16M @40M
  unsigned short* xb   = (unsigned short*)(ws + (size_t)58720256); // 8M  @56M
  unsigned short* cb   = (unsigned short*)(ws + (size_t)67108864); // 8M  @64M
  unsigned short* wqb  = (unsigned short*)(ws + (size_t)75497472); // 4M  @72M
  unsigned short* wkvb = (unsigned short*)(ws + (size_t)79691776); // 4M  @76M
  unsigned short* wop  = (unsigned short*)(ws + (size_t)83886080); // 4M  @80M

  const dim3 blk(256);
  pack_all<<<dim3(13312), blk, 0, stream>>>(x, Wq, ctx, Wkv, Wo, xb, wqb, cb, wkvb, wop);
  gemm_nt_bf16<1><<<dim3(512), blk, 0, stream>>>(xb, wqb, 4096, 2048,
                                                 cosb, sinb, qnw, Qb, gate, 0.125f * LOG2E_);
  gemm_nt_bf16<2><<<dim3(512), blk, 0, stream>>>(cb, wkvb, 4096, 2048,
                                                 cosb, sinb, knw, Kb, Vt, 1.0f);
  flash_bf16<<<dim3(16, 16, 2), blk, 0, stream>>>(Qb, Kb, Vt, gate, gpk);
  gemm_nt_hilo<<<dim3(256), blk, 0, stream>>>(gpk, wop, out, 4096, 1024, bo);
}